// Round 5
// baseline (1073.987 us; speedup 1.0000x reference)
//
#include <hip/hip_runtime.h>
#include <math.h>

#define NN 100000
#define NE 1600000
#define NB 391  // ceil(NN/256)

__device__ inline unsigned short f2bf(float f) {
  unsigned int u = __float_as_uint(f);
  u = u + 0x7fffu + ((u >> 16) & 1u);
  return (unsigned short)(u >> 16);
}
__device__ inline float bf2f(unsigned short h) {
  return __uint_as_float(((unsigned int)h) << 16);
}

// ---------------- CSR build ----------------
__global__ __launch_bounds__(256) void k_zero(int* __restrict__ deg) {
  int i = blockIdx.x * 256 + threadIdx.x;
  if (i < NN) deg[i] = 0;
}

__global__ __launch_bounds__(256) void k_hist(const int* __restrict__ dst, int* __restrict__ deg) {
  int e = blockIdx.x * 256 + threadIdx.x;
  if (e < NE) atomicAdd(&deg[dst[e]], 1);
}

__global__ __launch_bounds__(256) void k_scan1(const int* __restrict__ deg, int* __restrict__ tmp,
                                               int* __restrict__ bsum) {
  __shared__ int wsum[4];
  int i = blockIdx.x * 256 + threadIdx.x;
  int v = (i < NN) ? deg[i] : 0;
  int x = v;
#pragma unroll
  for (int d = 1; d < 64; d <<= 1) {
    int y = __shfl_up(x, d);
    if ((threadIdx.x & 63) >= d) x += y;
  }
  if ((threadIdx.x & 63) == 63) wsum[threadIdx.x >> 6] = x;
  __syncthreads();
  int add = 0;
  for (int w = 0; w < (threadIdx.x >> 6); ++w) add += wsum[w];
  int incl = x + add;
  if (i < NN) tmp[i] = incl - v;
  if (threadIdx.x == 255) bsum[blockIdx.x] = incl;
}

__global__ void k_scan2(const int* __restrict__ bsum, int* __restrict__ boff) {
  if (threadIdx.x == 0) {
    int run = 0;
    for (int b = 0; b < NB; ++b) { boff[b] = run; run += bsum[b]; }
  }
}

__global__ __launch_bounds__(256) void k_scan3(const int* __restrict__ deg, int* __restrict__ tmp,
                                               const int* __restrict__ boff, int* __restrict__ rs,
                                               float* __restrict__ dinv) {
  int i = blockIdx.x * 256 + threadIdx.x;
  if (i < NN) {
    int v = tmp[i] + boff[blockIdx.x];
    rs[i] = v;
    tmp[i] = v;  // becomes the atomic cursor for k_fill
    dinv[i] = rsqrtf((float)(deg[i] + 1));
  }
  if (i == 0) rs[NN] = NE;
}

// srcs[p] = src, de2[p] = (dst, original edge id)
__global__ __launch_bounds__(256) void k_fill(const int* __restrict__ src, const int* __restrict__ dst,
                                              int* __restrict__ cursor, int* __restrict__ srcs,
                                              int2* __restrict__ de2) {
  int e = blockIdx.x * 256 + threadIdx.x;
  if (e < NE) {
    int d = dst[e];
    int p = atomicAdd(&cursor[d], 1);
    srcs[p] = src[e];
    de2[p] = make_int2(d, e);
  }
}

// ---------------- GEMM fp32 in -> bf16 out (optionally row-scaled): Y = scale[r] * (X @ W) ----------------
__global__ __launch_bounds__(256) void k_gemm128(const float* __restrict__ X, const float* __restrict__ W,
                                                 unsigned short* __restrict__ Y,
                                                 const float* __restrict__ scale, int nrows) {
  __shared__ float Wl[128 * 128];
  const float4* W4 = (const float4*)W;
  float4* Wl4 = (float4*)Wl;
#pragma unroll
  for (int i = 0; i < 16; ++i) Wl4[threadIdx.x + i * 256] = W4[threadIdx.x + i * 256];
  __syncthreads();

  const int tc = threadIdx.x & 15;
  const int tr = threadIdx.x >> 4;
  const int r0 = blockIdx.x * 64 + tr * 4;
  const int c0 = tc * 8;

  float acc[4][8];
#pragma unroll
  for (int i = 0; i < 4; ++i)
#pragma unroll
    for (int j = 0; j < 8; ++j) acc[i][j] = 0.f;

  for (int k0 = 0; k0 < 128; k0 += 4) {
    float4 xv[4];
#pragma unroll
    for (int i = 0; i < 4; ++i) {
      int r = r0 + i;
      xv[i] = (r < nrows) ? *(const float4*)(X + (size_t)r * 128 + k0)
                          : make_float4(0.f, 0.f, 0.f, 0.f);
    }
#pragma unroll
    for (int kk = 0; kk < 4; ++kk) {
      float4 wa = *(const float4*)(Wl + (k0 + kk) * 128 + c0);
      float4 wb = *(const float4*)(Wl + (k0 + kk) * 128 + c0 + 4);
      float wv[8] = {wa.x, wa.y, wa.z, wa.w, wb.x, wb.y, wb.z, wb.w};
#pragma unroll
      for (int i = 0; i < 4; ++i) {
        float xs = reinterpret_cast<const float*>(&xv[i])[kk];
#pragma unroll
        for (int j = 0; j < 8; ++j) acc[i][j] = fmaf(xs, wv[j], acc[i][j]);
      }
    }
  }

#pragma unroll
  for (int i = 0; i < 4; ++i) {
    int r = r0 + i;
    if (r < nrows) {
      float sc = scale ? scale[r] : 1.f;
      unsigned short h[8];
#pragma unroll
      for (int j = 0; j < 8; ++j) h[j] = f2bf(acc[i][j] * sc);
      *(uint4*)(Y + (size_t)r * 128 + c0) = *(const uint4*)h;
    }
  }
}

// ---------------- GEMM bf16 in -> bf16 out: Y = X @ W ----------------
__global__ __launch_bounds__(256) void k_gemm128b(const unsigned short* __restrict__ X,
                                                  const float* __restrict__ W,
                                                  unsigned short* __restrict__ Y, int nrows) {
  __shared__ float Wl[128 * 128];
  const float4* W4 = (const float4*)W;
  float4* Wl4 = (float4*)Wl;
#pragma unroll
  for (int i = 0; i < 16; ++i) Wl4[threadIdx.x + i * 256] = W4[threadIdx.x + i * 256];
  __syncthreads();

  const int tc = threadIdx.x & 15;
  const int tr = threadIdx.x >> 4;
  const int r0 = blockIdx.x * 64 + tr * 4;
  const int c0 = tc * 8;

  float acc[4][8];
#pragma unroll
  for (int i = 0; i < 4; ++i)
#pragma unroll
    for (int j = 0; j < 8; ++j) acc[i][j] = 0.f;

  for (int k0 = 0; k0 < 128; k0 += 8) {
    uint4 xv[4];
#pragma unroll
    for (int i = 0; i < 4; ++i) {
      int r = r0 + i;
      xv[i] = (r < nrows) ? *(const uint4*)(X + (size_t)r * 128 + k0)
                          : make_uint4(0u, 0u, 0u, 0u);
    }
#pragma unroll
    for (int kk = 0; kk < 8; ++kk) {
      float4 wa = *(const float4*)(Wl + (k0 + kk) * 128 + c0);
      float4 wb = *(const float4*)(Wl + (k0 + kk) * 128 + c0 + 4);
      float wv[8] = {wa.x, wa.y, wa.z, wa.w, wb.x, wb.y, wb.z, wb.w};
#pragma unroll
      for (int i = 0; i < 4; ++i) {
        const unsigned short* px = (const unsigned short*)&xv[i];
        float xs = bf2f(px[kk]);
#pragma unroll
        for (int j = 0; j < 8; ++j) acc[i][j] = fmaf(xs, wv[j], acc[i][j]);
      }
    }
  }

#pragma unroll
  for (int i = 0; i < 4; ++i) {
    int r = r0 + i;
    if (r < nrows) {
      unsigned short h[8];
#pragma unroll
      for (int j = 0; j < 8; ++j) h[j] = f2bf(acc[i][j]);
      *(uint4*)(Y + (size_t)r * 128 + c0) = *(const uint4*)h;
    }
  }
}

// ---------------- fused aggregate (T pre-scaled by dinv[row]):
// out[d] = relu(dinv[d]*(T'[d] + sum_s T'[s]) + b)
__global__ __launch_bounds__(256) void k_agg(const unsigned short* __restrict__ T,
                                             const int* __restrict__ rs, const int* __restrict__ srcs,
                                             const float* __restrict__ dinv, const float* __restrict__ bias,
                                             float* __restrict__ outF, unsigned short* __restrict__ outB) {
  int node = blockIdx.x * 4 + (threadIdx.x >> 6);
  if (node >= NN) return;
  int lane = threadIdx.x & 63;
  int beg = rs[node], end = rs[node + 1];
  float dn = dinv[node];

  unsigned int sv = *(const unsigned int*)(T + (size_t)node * 128 + lane * 2);
  float ax = bf2f((unsigned short)(sv & 0xffff));
  float ay = bf2f((unsigned short)(sv >> 16));
  float bx = 0.f, by = 0.f;

  int j = beg;
  for (; j + 2 <= end; j += 2) {
    int s0 = srcs[j];
    int s1 = srcs[j + 1];
    unsigned int h0 = *(const unsigned int*)(T + (size_t)s0 * 128 + lane * 2);
    unsigned int h1 = *(const unsigned int*)(T + (size_t)s1 * 128 + lane * 2);
    ax += bf2f((unsigned short)(h0 & 0xffff));
    ay += bf2f((unsigned short)(h0 >> 16));
    bx += bf2f((unsigned short)(h1 & 0xffff));
    by += bf2f((unsigned short)(h1 >> 16));
  }
  if (j < end) {
    int s0 = srcs[j];
    unsigned int h0 = *(const unsigned int*)(T + (size_t)s0 * 128 + lane * 2);
    ax += bf2f((unsigned short)(h0 & 0xffff));
    ay += bf2f((unsigned short)(h0 >> 16));
  }
  ax += bx;
  ay += by;

  float2 bb = *(const float2*)(bias + lane * 2);
  float ox = fmaxf(fmaf(dn, ax, bb.x), 0.f);
  float oy = fmaxf(fmaf(dn, ay, bb.y), 0.f);
  if (outB) {
    unsigned int pv = (unsigned int)f2bf(ox) | ((unsigned int)f2bf(oy) << 16);
    *(unsigned int*)(outB + (size_t)node * 128 + lane * 2) = pv;
  } else {
    *(float2*)(outF + (size_t)node * 128 + lane * 2) = make_float2(ox, oy);
  }
}

// ---------------- edge epilogue, batched LDS-transpose reduce ----------------
// one wave per 64 CSR-ordered edges. out[eid] = sigmoid(relu(u[s]+v[d]+bm1).Wm2 + b2)
__global__ __launch_bounds__(128) void k_edge(const unsigned short* __restrict__ u,
                                              const unsigned short* __restrict__ v,
                                              const int* __restrict__ srcs, const int2* __restrict__ de2,
                                              const float* __restrict__ bm1, const float* __restrict__ Wm2,
                                              const float* __restrict__ bm2, float* __restrict__ out) {
  __shared__ float red[2][64 * 65];
  const int w = threadIdx.x >> 6;
  const int lane = threadIdx.x & 63;
  float* __restrict__ myred = &red[w][0];

  const int bat = blockIdx.x * 2 + w;   // < 25000, NE = 64*25000 exactly
  const int jb = bat * 64;

  float2 bmv = *(const float2*)(bm1 + lane * 2);
  float2 w2 = *(const float2*)(Wm2 + lane * 2);
  const float b2 = bm2[0];

  int cur = -1;
  float vb0 = 0.f, vb1 = 0.f;

#pragma unroll 2
  for (int c = 0; c < 64; ++c) {
    int j = jb + c;
    int s = srcs[j];
    int d = de2[j].x;
    unsigned int uu = *(const unsigned int*)(u + (size_t)s * 128 + lane * 2);
    if (d != cur) {
      unsigned int vv = *(const unsigned int*)(v + (size_t)d * 128 + lane * 2);
      vb0 = bf2f((unsigned short)(vv & 0xffff)) + bmv.x;
      vb1 = bf2f((unsigned short)(vv >> 16)) + bmv.y;
      cur = d;
    }
    float z0 = fmaxf(bf2f((unsigned short)(uu & 0xffff)) + vb0, 0.f);
    float z1 = fmaxf(bf2f((unsigned short)(uu >> 16)) + vb1, 0.f);
    myred[c * 65 + lane] = fmaf(z0, w2.x, z1 * w2.y);
  }

  // lane c reduces row c (2-way bank aliasing only)
  float s0 = 0.f, s1 = 0.f;
  const float* row = &myred[lane * 65];
#pragma unroll 8
  for (int k = 0; k < 64; k += 2) {
    s0 += row[k];
    s1 += row[k + 1];
  }
  float logit = s0 + s1 + b2;
  int eid = de2[jb + lane].y;
  out[eid] = 1.f / (1.f + __expf(-logit));
}

// ---------------- launch ----------------
extern "C" void kernel_launch(void* const* d_in, const int* in_sizes, int n_in,
                              void* d_out, int out_size, void* d_ws, size_t ws_size,
                              hipStream_t stream) {
  const float* x   = (const float*)d_in[0];
  const int* ei    = (const int*)d_in[1];
  const float* W1  = (const float*)d_in[2];
  const float* b1  = (const float*)d_in[3];
  const float* W2  = (const float*)d_in[4];
  const float* b2  = (const float*)d_in[5];
  const float* Wm1 = (const float*)d_in[6];
  const float* bm1 = (const float*)d_in[7];
  const float* Wm2 = (const float*)d_in[8];
  const float* bm2 = (const float*)d_in[9];
  float* out = (float*)d_out;

  const int* src = ei;
  const int* dst = ei + NE;

  // workspace layout (high-water 98,385,920 B; round-1 proved ws_size >= 102.8 MB)
  char* ws = (char*)d_ws;
  int*   deg    = (int*)(ws + 0x000000);   // 400 KB
  int*   rs     = (int*)(ws + 0x080000);   // 400 KB (+4)
  int*   cursor = (int*)(ws + 0x100000);   // 400 KB
  float* dinv   = (float*)(ws + 0x180000); // 400 KB
  int*   bsum   = (int*)(ws + 0x200000);
  int*   boff   = (int*)(ws + 0x210000);
  int*   srcs   = (int*)(ws + 0x220000);   // 6.4 MB -> ends 8,628,224
  int2*  de2    = (int2*)(ws + 0x840000);  // 12.8 MB -> ends 21,450,752
  unsigned short* bufT = (unsigned short*)(ws + 0x1480000);  // 25.6 MB -> ends 47,095,808
  float* bufH   = (float*)(ws + 0x2D00000);                  // starts 47,185,920 (NO overlap with bufT)
  unsigned short* hb   = (unsigned short*)bufH;              // bf16 h2 (first 25.6 MB of bufH)
  unsigned short* ubuf = bufT;
  unsigned short* vbuf = (unsigned short*)((char*)bufH + 25600000);

  const int gN = NB;
  const int gE = (NE + 255) / 256;
  const int gRow = (NN + 63) / 64;
  const int gAgg = (NN + 3) / 4;
  const int gEdge = 25000 / 2;  // 2 waves (batches) per block

  // CSR build
  k_zero<<<gN, 256, 0, stream>>>(deg);
  k_hist<<<gE, 256, 0, stream>>>(dst, deg);
  k_scan1<<<gN, 256, 0, stream>>>(deg, cursor, bsum);
  k_scan2<<<1, 64, 0, stream>>>(bsum, boff);
  k_scan3<<<gN, 256, 0, stream>>>(deg, cursor, boff, rs, dinv);
  k_fill<<<gE, 256, 0, stream>>>(src, dst, cursor, srcs, de2);

  // layer 1: T1' = dinv*(x@W1) (bf16); h1 = agg (fp32)
  k_gemm128<<<gRow, 256, 0, stream>>>(x, W1, bufT, dinv, NN);
  k_agg<<<gAgg, 256, 0, stream>>>(bufT, rs, srcs, dinv, b1, bufH, (unsigned short*)0);

  // layer 2: T2' = dinv*(h1@W2) (bf16); h2 = agg (bf16)
  k_gemm128<<<gRow, 256, 0, stream>>>(bufH, W2, bufT, dinv, NN);
  k_agg<<<gAgg, 256, 0, stream>>>(bufT, rs, srcs, dinv, b2, (float*)0, hb);

  // u = h2 @ Wm1_top, v = h2 @ Wm1_bot
  k_gemm128b<<<gRow, 256, 0, stream>>>(hb, Wm1, ubuf, NN);
  k_gemm128b<<<gRow, 256, 0, stream>>>(hb, Wm1 + 128 * 128, vbuf, NN);

  // edge epilogue
  k_edge<<<gEdge, 128, 0, stream>>>(ubuf, vbuf, srcs, de2, bm1, Wm2, bm2, out);
}

// Round 6
// 765.972 us; speedup vs baseline: 1.4021x; 1.4021x over previous
//
#include <hip/hip_runtime.h>
#include <math.h>

#define NN 100000
#define NE 1600000
#define NB 391  // ceil(NN/256)

__device__ inline unsigned short f2bf(float f) {
  unsigned int u = __float_as_uint(f);
  u = u + 0x7fffu + ((u >> 16) & 1u);
  return (unsigned short)(u >> 16);
}
__device__ inline float bf2f(unsigned short h) {
  return __uint_as_float(((unsigned int)h) << 16);
}

// ---------------- CSR build ----------------
__global__ __launch_bounds__(256) void k_zero(int* __restrict__ deg) {
  int i = blockIdx.x * 256 + threadIdx.x;
  if (i < NN) deg[i] = 0;
}

__global__ __launch_bounds__(256) void k_hist(const int* __restrict__ dst, int* __restrict__ deg) {
  int e = blockIdx.x * 256 + threadIdx.x;
  if (e < NE) atomicAdd(&deg[dst[e]], 1);
}

__global__ __launch_bounds__(256) void k_scan1(const int* __restrict__ deg, int* __restrict__ tmp,
                                               int* __restrict__ bsum) {
  __shared__ int wsum[4];
  int i = blockIdx.x * 256 + threadIdx.x;
  int v = (i < NN) ? deg[i] : 0;
  int x = v;
#pragma unroll
  for (int d = 1; d < 64; d <<= 1) {
    int y = __shfl_up(x, d);
    if ((threadIdx.x & 63) >= d) x += y;
  }
  if ((threadIdx.x & 63) == 63) wsum[threadIdx.x >> 6] = x;
  __syncthreads();
  int add = 0;
  for (int w = 0; w < (threadIdx.x >> 6); ++w) add += wsum[w];
  int incl = x + add;
  if (i < NN) tmp[i] = incl - v;
  if (threadIdx.x == 255) bsum[blockIdx.x] = incl;
}

__global__ void k_scan2(const int* __restrict__ bsum, int* __restrict__ boff) {
  if (threadIdx.x == 0) {
    int run = 0;
    for (int b = 0; b < NB; ++b) { boff[b] = run; run += bsum[b]; }
  }
}

__global__ __launch_bounds__(256) void k_scan3(const int* __restrict__ deg, int* __restrict__ tmp,
                                               const int* __restrict__ boff, int* __restrict__ rs,
                                               float* __restrict__ dinv) {
  int i = blockIdx.x * 256 + threadIdx.x;
  if (i < NN) {
    int v = tmp[i] + boff[blockIdx.x];
    rs[i] = v;
    tmp[i] = v;  // becomes the atomic cursor for k_fill
    dinv[i] = rsqrtf((float)(deg[i] + 1));
  }
  if (i == 0) rs[NN] = NE;
}

// srcs[p] = src, de2[p] = (dst, original edge id)
__global__ __launch_bounds__(256) void k_fill(const int* __restrict__ src, const int* __restrict__ dst,
                                              int* __restrict__ cursor, int* __restrict__ srcs,
                                              int2* __restrict__ de2) {
  int e = blockIdx.x * 256 + threadIdx.x;
  if (e < NE) {
    int d = dst[e];
    int p = atomicAdd(&cursor[d], 1);
    srcs[p] = src[e];
    de2[p] = make_int2(d, e);
  }
}

// ---------------- GEMM fp32 in -> bf16 out (optionally row-scaled): Y = scale[r] * (X @ W) ----------------
__global__ __launch_bounds__(256) void k_gemm128(const float* __restrict__ X, const float* __restrict__ W,
                                                 unsigned short* __restrict__ Y,
                                                 const float* __restrict__ scale, int nrows) {
  __shared__ float Wl[128 * 128];
  const float4* W4 = (const float4*)W;
  float4* Wl4 = (float4*)Wl;
#pragma unroll
  for (int i = 0; i < 16; ++i) Wl4[threadIdx.x + i * 256] = W4[threadIdx.x + i * 256];
  __syncthreads();

  const int tc = threadIdx.x & 15;
  const int tr = threadIdx.x >> 4;
  const int r0 = blockIdx.x * 64 + tr * 4;
  const int c0 = tc * 8;

  float acc[4][8];
#pragma unroll
  for (int i = 0; i < 4; ++i)
#pragma unroll
    for (int j = 0; j < 8; ++j) acc[i][j] = 0.f;

  for (int k0 = 0; k0 < 128; k0 += 4) {
    float4 xv[4];
#pragma unroll
    for (int i = 0; i < 4; ++i) {
      int r = r0 + i;
      xv[i] = (r < nrows) ? *(const float4*)(X + (size_t)r * 128 + k0)
                          : make_float4(0.f, 0.f, 0.f, 0.f);
    }
#pragma unroll
    for (int kk = 0; kk < 4; ++kk) {
      float4 wa = *(const float4*)(Wl + (k0 + kk) * 128 + c0);
      float4 wb = *(const float4*)(Wl + (k0 + kk) * 128 + c0 + 4);
      float wv[8] = {wa.x, wa.y, wa.z, wa.w, wb.x, wb.y, wb.z, wb.w};
#pragma unroll
      for (int i = 0; i < 4; ++i) {
        float xs = reinterpret_cast<const float*>(&xv[i])[kk];
#pragma unroll
        for (int j = 0; j < 8; ++j) acc[i][j] = fmaf(xs, wv[j], acc[i][j]);
      }
    }
  }

#pragma unroll
  for (int i = 0; i < 4; ++i) {
    int r = r0 + i;
    if (r < nrows) {
      float sc = scale ? scale[r] : 1.f;
      unsigned short h[8];
#pragma unroll
      for (int j = 0; j < 8; ++j) h[j] = f2bf(acc[i][j] * sc);
      *(uint4*)(Y + (size_t)r * 128 + c0) = *(const uint4*)h;
    }
  }
}

// ---------------- GEMM bf16 in -> bf16 out: Y = X @ W ----------------
__global__ __launch_bounds__(256) void k_gemm128b(const unsigned short* __restrict__ X,
                                                  const float* __restrict__ W,
                                                  unsigned short* __restrict__ Y, int nrows) {
  __shared__ float Wl[128 * 128];
  const float4* W4 = (const float4*)W;
  float4* Wl4 = (float4*)Wl;
#pragma unroll
  for (int i = 0; i < 16; ++i) Wl4[threadIdx.x + i * 256] = W4[threadIdx.x + i * 256];
  __syncthreads();

  const int tc = threadIdx.x & 15;
  const int tr = threadIdx.x >> 4;
  const int r0 = blockIdx.x * 64 + tr * 4;
  const int c0 = tc * 8;

  float acc[4][8];
#pragma unroll
  for (int i = 0; i < 4; ++i)
#pragma unroll
    for (int j = 0; j < 8; ++j) acc[i][j] = 0.f;

  for (int k0 = 0; k0 < 128; k0 += 8) {
    uint4 xv[4];
#pragma unroll
    for (int i = 0; i < 4; ++i) {
      int r = r0 + i;
      xv[i] = (r < nrows) ? *(const uint4*)(X + (size_t)r * 128 + k0)
                          : make_uint4(0u, 0u, 0u, 0u);
    }
#pragma unroll
    for (int kk = 0; kk < 8; ++kk) {
      float4 wa = *(const float4*)(Wl + (k0 + kk) * 128 + c0);
      float4 wb = *(const float4*)(Wl + (k0 + kk) * 128 + c0 + 4);
      float wv[8] = {wa.x, wa.y, wa.z, wa.w, wb.x, wb.y, wb.z, wb.w};
#pragma unroll
      for (int i = 0; i < 4; ++i) {
        const unsigned short* px = (const unsigned short*)&xv[i];
        float xs = bf2f(px[kk]);
#pragma unroll
        for (int j = 0; j < 8; ++j) acc[i][j] = fmaf(xs, wv[j], acc[i][j]);
      }
    }
  }

#pragma unroll
  for (int i = 0; i < 4; ++i) {
    int r = r0 + i;
    if (r < nrows) {
      unsigned short h[8];
#pragma unroll
      for (int j = 0; j < 8; ++j) h[j] = f2bf(acc[i][j]);
      *(uint4*)(Y + (size_t)r * 128 + c0) = *(const uint4*)h;
    }
  }
}

// ---------------- fused aggregate (T pre-scaled by dinv[row]):
// out[d] = relu(dinv[d]*(T'[d] + sum_s T'[s]) + b)
// chunk-load 64 srcs coalesced per wave, readlane-broadcast -> single gather chain
__global__ __launch_bounds__(256) void k_agg(const unsigned short* __restrict__ T,
                                             const int* __restrict__ rs, const int* __restrict__ srcs,
                                             const float* __restrict__ dinv, const float* __restrict__ bias,
                                             float* __restrict__ outF, unsigned short* __restrict__ outB) {
  int node = blockIdx.x * 4 + (threadIdx.x >> 6);
  if (node >= NN) return;
  int lane = threadIdx.x & 63;
  int beg = rs[node], end = rs[node + 1];
  float dn = dinv[node];

  unsigned int sv = *(const unsigned int*)(T + (size_t)node * 128 + lane * 2);
  float ax = bf2f((unsigned short)(sv & 0xffff));
  float ay = bf2f((unsigned short)(sv >> 16));
  float bx = 0.f, by = 0.f;

  for (int j0 = beg; j0 < end; j0 += 64) {
    int sl = (j0 + lane < end) ? srcs[j0 + lane] : 0;
    int n = end - j0;
    if (n > 64) n = 64;
    int c = 0;
    for (; c + 2 <= n; c += 2) {
      int s0 = __builtin_amdgcn_readlane(sl, c);
      int s1 = __builtin_amdgcn_readlane(sl, c + 1);
      unsigned int h0 = *(const unsigned int*)(T + (size_t)s0 * 128 + lane * 2);
      unsigned int h1 = *(const unsigned int*)(T + (size_t)s1 * 128 + lane * 2);
      ax += bf2f((unsigned short)(h0 & 0xffff));
      ay += bf2f((unsigned short)(h0 >> 16));
      bx += bf2f((unsigned short)(h1 & 0xffff));
      by += bf2f((unsigned short)(h1 >> 16));
    }
    if (c < n) {
      int s0 = __builtin_amdgcn_readlane(sl, c);
      unsigned int h0 = *(const unsigned int*)(T + (size_t)s0 * 128 + lane * 2);
      ax += bf2f((unsigned short)(h0 & 0xffff));
      ay += bf2f((unsigned short)(h0 >> 16));
    }
  }
  ax += bx;
  ay += by;

  float2 bb = *(const float2*)(bias + lane * 2);
  float ox = fmaxf(fmaf(dn, ax, bb.x), 0.f);
  float oy = fmaxf(fmaf(dn, ay, bb.y), 0.f);
  if (outB) {
    unsigned int pv = (unsigned int)f2bf(ox) | ((unsigned int)f2bf(oy) << 16);
    *(unsigned int*)(outB + (size_t)node * 128 + lane * 2) = pv;
  } else {
    *(float2*)(outF + (size_t)node * 128 + lane * 2) = make_float2(ox, oy);
  }
}

// ---------------- edge epilogue, batched LDS-transpose reduce (occupancy-fixed) ----------------
// 4 waves/block; each wave owns a 64-edge batch, processed as two 32-edge LDS passes.
// LDS/block = 4*32*65*4 = 33,280 B -> 4 blocks/CU = 16 waves/CU.
__global__ __launch_bounds__(256) void k_edge(const unsigned short* __restrict__ u,
                                              const unsigned short* __restrict__ v,
                                              const int* __restrict__ srcs, const int2* __restrict__ de2,
                                              const float* __restrict__ bm1, const float* __restrict__ Wm2,
                                              const float* __restrict__ bm2, float* __restrict__ out) {
  __shared__ float red[4][32 * 65];
  const int w = threadIdx.x >> 6;
  const int lane = threadIdx.x & 63;
  float* __restrict__ myred = &red[w][0];

  const int bat = blockIdx.x * 4 + w;  // < 25000 (NE = 64*25000 exactly)
  const int jb = bat * 64;

  float2 bmv = *(const float2*)(bm1 + lane * 2);
  float2 w2 = *(const float2*)(Wm2 + lane * 2);
  const float b2 = bm2[0];

  // coalesced per-lane index loads for the whole 64-edge batch
  const int es = srcs[jb + lane];
  const int2 ed = de2[jb + lane];

  int cur = -1;
  float vb0 = 0.f, vb1 = 0.f;

#pragma unroll
  for (int h2 = 0; h2 < 2; ++h2) {
#pragma unroll 8
    for (int c = 0; c < 32; ++c) {
      int idx = h2 * 32 + c;
      int s = __builtin_amdgcn_readlane(es, idx);
      int d = __builtin_amdgcn_readlane(ed.x, idx);
      unsigned int uu = *(const unsigned int*)(u + (size_t)s * 128 + lane * 2);
      if (d != cur) {
        unsigned int vv = *(const unsigned int*)(v + (size_t)d * 128 + lane * 2);
        vb0 = bf2f((unsigned short)(vv & 0xffff)) + bmv.x;
        vb1 = bf2f((unsigned short)(vv >> 16)) + bmv.y;
        cur = d;
      }
      float z0 = fmaxf(bf2f((unsigned short)(uu & 0xffff)) + vb0, 0.f);
      float z1 = fmaxf(bf2f((unsigned short)(uu >> 16)) + vb1, 0.f);
      myred[c * 65 + lane] = fmaf(z0, w2.x, z1 * w2.y);
    }
    __syncthreads();  // order LDS writes vs cross-lane reads (uniform control flow)

    // lane L reduces half (L>>5) of row (L&31); stride 65 -> 2-way bank alias (free)
    int cr = lane & 31, hh = lane >> 5;
    const float* row = &myred[cr * 65 + hh * 32];
    float s0 = 0.f, s1 = 0.f;
#pragma unroll
    for (int k = 0; k < 32; k += 2) {
      s0 += row[k];
      s1 += row[k + 1];
    }
    float s = s0 + s1;
    s += __shfl_xor(s, 32);
    float sg = 1.f / (1.f + __expf(-(s + b2)));
    int eid = __shfl(ed.y, h2 * 32 + cr);
    if (hh == 0) out[eid] = sg;
    __syncthreads();  // protect tile before next pass overwrites
  }
}

// ---------------- launch ----------------
extern "C" void kernel_launch(void* const* d_in, const int* in_sizes, int n_in,
                              void* d_out, int out_size, void* d_ws, size_t ws_size,
                              hipStream_t stream) {
  const float* x   = (const float*)d_in[0];
  const int* ei    = (const int*)d_in[1];
  const float* W1  = (const float*)d_in[2];
  const float* b1  = (const float*)d_in[3];
  const float* W2  = (const float*)d_in[4];
  const float* b2  = (const float*)d_in[5];
  const float* Wm1 = (const float*)d_in[6];
  const float* bm1 = (const float*)d_in[7];
  const float* Wm2 = (const float*)d_in[8];
  const float* bm2 = (const float*)d_in[9];
  float* out = (float*)d_out;

  const int* src = ei;
  const int* dst = ei + NE;

  // workspace layout (high-water 98.4 MB; round-1 proved ws_size >= 102.8 MB)
  char* ws = (char*)d_ws;
  int*   deg    = (int*)(ws + 0x000000);   // 400 KB
  int*   rs     = (int*)(ws + 0x080000);   // 400 KB (+4)
  int*   cursor = (int*)(ws + 0x100000);   // 400 KB
  float* dinv   = (float*)(ws + 0x180000); // 400 KB
  int*   bsum   = (int*)(ws + 0x200000);
  int*   boff   = (int*)(ws + 0x210000);
  int*   srcs   = (int*)(ws + 0x220000);   // 6.4 MB -> ends 8,628,224
  int2*  de2    = (int2*)(ws + 0x840000);  // 12.8 MB -> ends 21,450,752
  unsigned short* bufT = (unsigned short*)(ws + 0x1480000);  // 25.6 MB -> ends 47,095,808
  float* bufH   = (float*)(ws + 0x2D00000);                  // starts 47,185,920 (no overlap)
  unsigned short* hb   = (unsigned short*)bufH;              // bf16 h2 (first 25.6 MB of bufH)
  unsigned short* ubuf = bufT;
  unsigned short* vbuf = (unsigned short*)((char*)bufH + 25600000);

  const int gN = NB;
  const int gE = (NE + 255) / 256;
  const int gRow = (NN + 63) / 64;
  const int gAgg = (NN + 3) / 4;
  const int gEdge = 25000 / 4;  // 4 waves (64-edge batches) per block; 25000 % 4 == 0

  // CSR build
  k_zero<<<gN, 256, 0, stream>>>(deg);
  k_hist<<<gE, 256, 0, stream>>>(dst, deg);
  k_scan1<<<gN, 256, 0, stream>>>(deg, cursor, bsum);
  k_scan2<<<1, 64, 0, stream>>>(bsum, boff);
  k_scan3<<<gN, 256, 0, stream>>>(deg, cursor, boff, rs, dinv);
  k_fill<<<gE, 256, 0, stream>>>(src, dst, cursor, srcs, de2);

  // layer 1: T1' = dinv*(x@W1) (bf16); h1 = agg (fp32)
  k_gemm128<<<gRow, 256, 0, stream>>>(x, W1, bufT, dinv, NN);
  k_agg<<<gAgg, 256, 0, stream>>>(bufT, rs, srcs, dinv, b1, bufH, (unsigned short*)0);

  // layer 2: T2' = dinv*(h1@W2) (bf16); h2 = agg (bf16)
  k_gemm128<<<gRow, 256, 0, stream>>>(bufH, W2, bufT, dinv, NN);
  k_agg<<<gAgg, 256, 0, stream>>>(bufT, rs, srcs, dinv, b2, (float*)0, hb);

  // u = h2 @ Wm1_top, v = h2 @ Wm1_bot
  k_gemm128b<<<gRow, 256, 0, stream>>>(hb, Wm1, ubuf, NN);
  k_gemm128b<<<gRow, 256, 0, stream>>>(hb, Wm1 + 128 * 128, vbuf, NN);

  // edge epilogue
  k_edge<<<gEdge, 256, 0, stream>>>(ubuf, vbuf, srcs, de2, bm1, Wm2, bm2, out);
}

// Round 7
// 514.743 us; speedup vs baseline: 2.0865x; 1.4881x over previous
//
#include <hip/hip_runtime.h>
#include <math.h>

#define NN 100000
#define NE 1600000
#define NB 391  // ceil(NN/256)

typedef __attribute__((ext_vector_type(8))) short bf16x8;
typedef __attribute__((ext_vector_type(4))) float f32x4;

__device__ inline unsigned short f2bf(float f) {
  unsigned int u = __float_as_uint(f);
  u = u + 0x7fffu + ((u >> 16) & 1u);
  return (unsigned short)(u >> 16);
}
__device__ inline float bf2f(unsigned short h) {
  return __uint_as_float(((unsigned int)h) << 16);
}

// ---------------- CSR build ----------------
__global__ __launch_bounds__(256) void k_zero(int* __restrict__ deg) {
  int i = blockIdx.x * 256 + threadIdx.x;
  if (i < NN) deg[i] = 0;
}

__global__ __launch_bounds__(256) void k_hist(const int* __restrict__ dst, int* __restrict__ deg) {
  int e = blockIdx.x * 256 + threadIdx.x;
  if (e < NE) atomicAdd(&deg[dst[e]], 1);
}

__global__ __launch_bounds__(256) void k_scan1(const int* __restrict__ deg, int* __restrict__ tmp,
                                               int* __restrict__ bsum) {
  __shared__ int wsum[4];
  int i = blockIdx.x * 256 + threadIdx.x;
  int v = (i < NN) ? deg[i] : 0;
  int x = v;
#pragma unroll
  for (int d = 1; d < 64; d <<= 1) {
    int y = __shfl_up(x, d);
    if ((threadIdx.x & 63) >= d) x += y;
  }
  if ((threadIdx.x & 63) == 63) wsum[threadIdx.x >> 6] = x;
  __syncthreads();
  int add = 0;
  for (int w = 0; w < (threadIdx.x >> 6); ++w) add += wsum[w];
  int incl = x + add;
  if (i < NN) tmp[i] = incl - v;
  if (threadIdx.x == 255) bsum[blockIdx.x] = incl;
}

__global__ void k_scan2(const int* __restrict__ bsum, int* __restrict__ boff) {
  if (threadIdx.x == 0) {
    int run = 0;
    for (int b = 0; b < NB; ++b) { boff[b] = run; run += bsum[b]; }
  }
}

__global__ __launch_bounds__(256) void k_scan3(const int* __restrict__ deg, int* __restrict__ tmp,
                                               const int* __restrict__ boff, int* __restrict__ rs,
                                               float* __restrict__ dinv) {
  int i = blockIdx.x * 256 + threadIdx.x;
  if (i < NN) {
    int v = tmp[i] + boff[blockIdx.x];
    rs[i] = v;
    tmp[i] = v;  // becomes the atomic cursor for k_fill
    dinv[i] = rsqrtf((float)(deg[i] + 1));
  }
  if (i == 0) rs[NN] = NE;
}

// srcs[p] = src, de2[p] = (dst, original edge id)
__global__ __launch_bounds__(256) void k_fill(const int* __restrict__ src, const int* __restrict__ dst,
                                              int* __restrict__ cursor, int* __restrict__ srcs,
                                              int2* __restrict__ de2) {
  int e = blockIdx.x * 256 + threadIdx.x;
  if (e < NE) {
    int d = dst[e];
    int p = atomicAdd(&cursor[d], 1);
    srcs[p] = src[e];
    de2[p] = make_int2(d, e);
  }
}

// ---------------- weight prep: fp32 [128][128] views -> bf16 B-fragment layout ----------------
// frag idx within matrix: ((f*4+t)*64+lane)*8+u  <->  n=f*16+(lane&15), k=t*32+(lane>>4)*8+u
// m=0: W1, m=1: W2, m=2: Wm1 rows 0..127, m=3: Wm1 rows 128..255
__global__ __launch_bounds__(256) void k_prep(const float* __restrict__ W1, const float* __restrict__ W2,
                                              const float* __restrict__ Wm1, unsigned short* __restrict__ Bp) {
  int gid = blockIdx.x * 256 + threadIdx.x;  // 0..65535
  int idx = gid & 16383;
  int m = gid >> 14;
  int u = idx & 7;
  int lane = (idx >> 3) & 63;
  int ft = idx >> 9;
  int t = ft & 3, f = ft >> 2;
  int n = f * 16 + (lane & 15);
  int k = t * 32 + (lane >> 4) * 8 + u;
  const float* Wsrc = (m == 0) ? W1 : (m == 1) ? W2 : Wm1;
  int krow = (m == 3) ? (k + 128) : k;
  Bp[gid] = f2bf(Wsrc[(size_t)krow * 128 + n]);
}

// ---------------- MFMA GEMM, bf16 A: Y = scale[r]? * (A @ W), K=N=128 ----------------
// 4 waves/block, 64 rows/block. Bp = prepped fragments (16384 bf16). LDS 32KB.
__global__ __launch_bounds__(256) void k_gemm_mfma(const unsigned short* __restrict__ A,
                                                   const unsigned short* __restrict__ Bp,
                                                   unsigned short* __restrict__ Y,
                                                   const float* __restrict__ scale, int nrows) {
  __shared__ unsigned short BL[16384];
  {
    const uint4* gp = (const uint4*)Bp;
    uint4* sp = (uint4*)BL;
#pragma unroll
    for (int i = 0; i < 8; ++i) sp[threadIdx.x + i * 256] = gp[threadIdx.x + i * 256];
  }
  __syncthreads();

  const int w = threadIdx.x >> 6, lane = threadIdx.x & 63;
  const int r = lane & 15, g = lane >> 4;
  const int rowbase = blockIdx.x * 64 + w * 16;
  const int arow = rowbase + r;

  bf16x8 av[4];
  if (arow < nrows) {
#pragma unroll
    for (int t = 0; t < 4; ++t) av[t] = *(const bf16x8*)(A + (size_t)arow * 128 + g * 8 + t * 32);
  } else {
#pragma unroll
    for (int t = 0; t < 4; ++t) av[t] = (bf16x8){0, 0, 0, 0, 0, 0, 0, 0};
  }

  f32x4 acc[8];
#pragma unroll
  for (int f = 0; f < 8; ++f) acc[f] = (f32x4){0.f, 0.f, 0.f, 0.f};

#pragma unroll
  for (int f = 0; f < 8; ++f)
#pragma unroll
    for (int t = 0; t < 4; ++t) {
      bf16x8 bv = *(const bf16x8*)(&BL[(((f << 2) | t) << 9) | (lane << 3)]);
      acc[f] = __builtin_amdgcn_mfma_f32_16x16x32_bf16(av[t], bv, acc[f], 0, 0, 0);
    }

#pragma unroll
  for (int j = 0; j < 4; ++j) {
    int row = rowbase + g * 4 + j;
    if (row < nrows) {
      float sc = scale ? scale[row] : 1.f;
#pragma unroll
      for (int f = 0; f < 8; ++f) Y[(size_t)row * 128 + f * 16 + r] = f2bf(acc[f][j] * sc);
    }
  }
}

// ---------------- MFMA GEMM, fp32 A (converts on the fly) ----------------
__global__ __launch_bounds__(256) void k_gemm_mfma_f32(const float* __restrict__ A,
                                                       const unsigned short* __restrict__ Bp,
                                                       unsigned short* __restrict__ Y,
                                                       const float* __restrict__ scale, int nrows) {
  __shared__ unsigned short BL[16384];
  {
    const uint4* gp = (const uint4*)Bp;
    uint4* sp = (uint4*)BL;
#pragma unroll
    for (int i = 0; i < 8; ++i) sp[threadIdx.x + i * 256] = gp[threadIdx.x + i * 256];
  }
  __syncthreads();

  const int w = threadIdx.x >> 6, lane = threadIdx.x & 63;
  const int r = lane & 15, g = lane >> 4;
  const int rowbase = blockIdx.x * 64 + w * 16;
  const int arow = rowbase + r;

  bf16x8 av[4];
  if (arow < nrows) {
#pragma unroll
    for (int t = 0; t < 4; ++t) {
      float4 a0 = *(const float4*)(A + (size_t)arow * 128 + g * 8 + t * 32);
      float4 a1 = *(const float4*)(A + (size_t)arow * 128 + g * 8 + t * 32 + 4);
      bf16x8 pk;
      pk[0] = (short)f2bf(a0.x); pk[1] = (short)f2bf(a0.y);
      pk[2] = (short)f2bf(a0.z); pk[3] = (short)f2bf(a0.w);
      pk[4] = (short)f2bf(a1.x); pk[5] = (short)f2bf(a1.y);
      pk[6] = (short)f2bf(a1.z); pk[7] = (short)f2bf(a1.w);
      av[t] = pk;
    }
  } else {
#pragma unroll
    for (int t = 0; t < 4; ++t) av[t] = (bf16x8){0, 0, 0, 0, 0, 0, 0, 0};
  }

  f32x4 acc[8];
#pragma unroll
  for (int f = 0; f < 8; ++f) acc[f] = (f32x4){0.f, 0.f, 0.f, 0.f};

#pragma unroll
  for (int f = 0; f < 8; ++f)
#pragma unroll
    for (int t = 0; t < 4; ++t) {
      bf16x8 bv = *(const bf16x8*)(&BL[(((f << 2) | t) << 9) | (lane << 3)]);
      acc[f] = __builtin_amdgcn_mfma_f32_16x16x32_bf16(av[t], bv, acc[f], 0, 0, 0);
    }

#pragma unroll
  for (int j = 0; j < 4; ++j) {
    int row = rowbase + g * 4 + j;
    if (row < nrows) {
      float sc = scale ? scale[row] : 1.f;
#pragma unroll
      for (int f = 0; f < 8; ++f) Y[(size_t)row * 128 + f * 16 + r] = f2bf(acc[f][j] * sc);
    }
  }
}

// ---------------- fused aggregate (T pre-scaled by dinv[row]):
// out[d] = relu(dinv[d]*(T'[d] + sum_s T'[s]) + b), bf16 out
__global__ __launch_bounds__(256) void k_agg(const unsigned short* __restrict__ T,
                                             const int* __restrict__ rs, const int* __restrict__ srcs,
                                             const float* __restrict__ dinv, const float* __restrict__ bias,
                                             unsigned short* __restrict__ outB) {
  int node = blockIdx.x * 4 + (threadIdx.x >> 6);
  if (node >= NN) return;
  int lane = threadIdx.x & 63;
  int beg = rs[node], end = rs[node + 1];
  float dn = dinv[node];

  unsigned int sv = *(const unsigned int*)(T + (size_t)node * 128 + lane * 2);
  float ax = bf2f((unsigned short)(sv & 0xffff));
  float ay = bf2f((unsigned short)(sv >> 16));
  float bx = 0.f, by = 0.f;

  for (int j0 = beg; j0 < end; j0 += 64) {
    int sl = (j0 + lane < end) ? srcs[j0 + lane] : 0;
    int n = end - j0;
    if (n > 64) n = 64;
    int c = 0;
    for (; c + 2 <= n; c += 2) {
      int s0 = __builtin_amdgcn_readlane(sl, c);
      int s1 = __builtin_amdgcn_readlane(sl, c + 1);
      unsigned int h0 = *(const unsigned int*)(T + (size_t)s0 * 128 + lane * 2);
      unsigned int h1 = *(const unsigned int*)(T + (size_t)s1 * 128 + lane * 2);
      ax += bf2f((unsigned short)(h0 & 0xffff));
      ay += bf2f((unsigned short)(h0 >> 16));
      bx += bf2f((unsigned short)(h1 & 0xffff));
      by += bf2f((unsigned short)(h1 >> 16));
    }
    if (c < n) {
      int s0 = __builtin_amdgcn_readlane(sl, c);
      unsigned int h0 = *(const unsigned int*)(T + (size_t)s0 * 128 + lane * 2);
      ax += bf2f((unsigned short)(h0 & 0xffff));
      ay += bf2f((unsigned short)(h0 >> 16));
    }
  }
  ax += bx;
  ay += by;

  float2 bb = *(const float2*)(bias + lane * 2);
  float ox = fmaxf(fmaf(dn, ax, bb.x), 0.f);
  float oy = fmaxf(fmaf(dn, ay, bb.y), 0.f);
  unsigned int pv = (unsigned int)f2bf(ox) | ((unsigned int)f2bf(oy) << 16);
  *(unsigned int*)(outB + (size_t)node * 128 + lane * 2) = pv;
}

// ---------------- edge epilogue, batched LDS-transpose reduce ----------------
__global__ __launch_bounds__(256) void k_edge(const unsigned short* __restrict__ u,
                                              const unsigned short* __restrict__ v,
                                              const int* __restrict__ srcs, const int2* __restrict__ de2,
                                              const float* __restrict__ bm1, const float* __restrict__ Wm2,
                                              const float* __restrict__ bm2, float* __restrict__ out) {
  __shared__ float red[4][32 * 65];
  const int w = threadIdx.x >> 6;
  const int lane = threadIdx.x & 63;
  float* __restrict__ myred = &red[w][0];

  const int bat = blockIdx.x * 4 + w;  // < 25000 (NE = 64*25000 exactly)
  const int jb = bat * 64;

  float2 bmv = *(const float2*)(bm1 + lane * 2);
  float2 w2 = *(const float2*)(Wm2 + lane * 2);
  const float b2 = bm2[0];

  const int es = srcs[jb + lane];
  const int2 ed = de2[jb + lane];

  int cur = -1;
  float vb0 = 0.f, vb1 = 0.f;

#pragma unroll
  for (int h2 = 0; h2 < 2; ++h2) {
#pragma unroll 8
    for (int c = 0; c < 32; ++c) {
      int idx = h2 * 32 + c;
      int s = __builtin_amdgcn_readlane(es, idx);
      int d = __builtin_amdgcn_readlane(ed.x, idx);
      unsigned int uu = *(const unsigned int*)(u + (size_t)s * 128 + lane * 2);
      if (d != cur) {
        unsigned int vv = *(const unsigned int*)(v + (size_t)d * 128 + lane * 2);
        vb0 = bf2f((unsigned short)(vv & 0xffff)) + bmv.x;
        vb1 = bf2f((unsigned short)(vv >> 16)) + bmv.y;
        cur = d;
      }
      float z0 = fmaxf(bf2f((unsigned short)(uu & 0xffff)) + vb0, 0.f);
      float z1 = fmaxf(bf2f((unsigned short)(uu >> 16)) + vb1, 0.f);
      myred[c * 65 + lane] = fmaf(z0, w2.x, z1 * w2.y);
    }
    __syncthreads();

    int cr = lane & 31, hh = lane >> 5;
    const float* row = &myred[cr * 65 + hh * 32];
    float s0 = 0.f, s1 = 0.f;
#pragma unroll
    for (int k = 0; k < 32; k += 2) {
      s0 += row[k];
      s1 += row[k + 1];
    }
    float s = s0 + s1;
    s += __shfl_xor(s, 32);
    float sg = 1.f / (1.f + __expf(-(s + b2)));
    int eid = __shfl(ed.y, h2 * 32 + cr);
    if (hh == 0) out[eid] = sg;
    __syncthreads();
  }
}

// ---------------- launch ----------------
extern "C" void kernel_launch(void* const* d_in, const int* in_sizes, int n_in,
                              void* d_out, int out_size, void* d_ws, size_t ws_size,
                              hipStream_t stream) {
  const float* x   = (const float*)d_in[0];
  const int* ei    = (const int*)d_in[1];
  const float* W1  = (const float*)d_in[2];
  const float* b1  = (const float*)d_in[3];
  const float* W2  = (const float*)d_in[4];
  const float* b2  = (const float*)d_in[5];
  const float* Wm1 = (const float*)d_in[6];
  const float* bm1 = (const float*)d_in[7];
  const float* Wm2 = (const float*)d_in[8];
  const float* bm2 = (const float*)d_in[9];
  float* out = (float*)d_out;

  const int* src = ei;
  const int* dst = ei + NE;

  // workspace layout (high-water 98,476,032 B; round-1 proved ws_size >= 102.8 MB)
  char* ws = (char*)d_ws;
  int*   deg    = (int*)(ws + 0x000000);   // 400 KB
  int*   rs     = (int*)(ws + 0x080000);   // 400 KB (+4)
  int*   cursor = (int*)(ws + 0x100000);   // 400 KB
  float* dinv   = (float*)(ws + 0x180000); // 400 KB
  int*   bsum   = (int*)(ws + 0x200000);
  int*   boff   = (int*)(ws + 0x210000);
  unsigned short* Bp = (unsigned short*)(ws + 0x220000);  // 4*32KB = 128 KB -> ends 0x240000
  int*   srcs   = (int*)(ws + 0x240000);   // 6.4 MB -> ends 8,759,296
  int2*  de2    = (int2*)(ws + 0x860000);  // 12.8 MB -> ends 21,581,824
  unsigned short* bufT = (unsigned short*)(ws + 0x14A0000);  // 25.6 MB -> ends 47,226,880
  unsigned short* hbuf = (unsigned short*)(ws + 0x2D10000);  // 25.6 MB -> ends 72,851,456
  unsigned short* vbuf = (unsigned short*)(ws + 0x4580000);  // 25.6 MB -> ends 98,476,032
  unsigned short* ubuf = bufT;

  const int gN = NB;
  const int gE = (NE + 255) / 256;
  const int gRow = (NN + 63) / 64;   // 1563
  const int gAgg = (NN + 3) / 4;
  const int gEdge = 25000 / 4;

  // CSR build + weight prep
  k_zero<<<gN, 256, 0, stream>>>(deg);
  k_hist<<<gE, 256, 0, stream>>>(dst, deg);
  k_scan1<<<gN, 256, 0, stream>>>(deg, cursor, bsum);
  k_scan2<<<1, 64, 0, stream>>>(bsum, boff);
  k_scan3<<<gN, 256, 0, stream>>>(deg, cursor, boff, rs, dinv);
  k_fill<<<gE, 256, 0, stream>>>(src, dst, cursor, srcs, de2);
  k_prep<<<256, 256, 0, stream>>>(W1, W2, Wm1, Bp);

  // layer 1: T1' = dinv*(x@W1) (bf16, MFMA); h1 = agg (bf16)
  k_gemm_mfma_f32<<<gRow, 256, 0, stream>>>(x, Bp, bufT, dinv, NN);
  k_agg<<<gAgg, 256, 0, stream>>>(bufT, rs, srcs, dinv, b1, hbuf);

  // layer 2: T2' = dinv*(h1@W2) (bf16, MFMA); h2 = agg (bf16)
  k_gemm_mfma<<<gRow, 256, 0, stream>>>(hbuf, Bp + 16384, bufT, dinv, NN);
  k_agg<<<gAgg, 256, 0, stream>>>(bufT, rs, srcs, dinv, b2, hbuf);

  // u = h2 @ Wm1_top, v = h2 @ Wm1_bot (MFMA)
  k_gemm_mfma<<<gRow, 256, 0, stream>>>(hbuf, Bp + 2 * 16384, ubuf, (const float*)0, NN);
  k_gemm_mfma<<<gRow, 256, 0, stream>>>(hbuf, Bp + 3 * 16384, vbuf, (const float*)0, NN);

  // edge epilogue
  k_edge<<<gEdge, 256, 0, stream>>>(ubuf, vbuf, srcs, de2, bm1, Wm2, bm2, out);
}

// Round 8
// 507.915 us; speedup vs baseline: 2.1145x; 1.0134x over previous
//
#include <hip/hip_runtime.h>
#include <math.h>

#define NN 100000
#define NE 1600000
#define NB 391  // ceil(NN/256)

typedef __attribute__((ext_vector_type(8))) short bf16x8;
typedef __attribute__((ext_vector_type(4))) float f32x4;

__device__ inline unsigned short f2bf(float f) {
  unsigned int u = __float_as_uint(f);
  u = u + 0x7fffu + ((u >> 16) & 1u);
  return (unsigned short)(u >> 16);
}
__device__ inline float bf2f(unsigned short h) {
  return __uint_as_float(((unsigned int)h) << 16);
}

// ---------------- CSR build ----------------
__global__ __launch_bounds__(256) void k_zero(int* __restrict__ deg) {
  int i = blockIdx.x * 256 + threadIdx.x;
  if (i < NN) deg[i] = 0;
}

__global__ __launch_bounds__(256) void k_hist(const int* __restrict__ dst, int* __restrict__ deg) {
  int e = blockIdx.x * 256 + threadIdx.x;
  if (e < NE) atomicAdd(&deg[dst[e]], 1);
}

__global__ __launch_bounds__(256) void k_scan1(const int* __restrict__ deg, int* __restrict__ tmp,
                                               int* __restrict__ bsum) {
  __shared__ int wsum[4];
  int i = blockIdx.x * 256 + threadIdx.x;
  int v = (i < NN) ? deg[i] : 0;
  int x = v;
#pragma unroll
  for (int d = 1; d < 64; d <<= 1) {
    int y = __shfl_up(x, d);
    if ((threadIdx.x & 63) >= d) x += y;
  }
  if ((threadIdx.x & 63) == 63) wsum[threadIdx.x >> 6] = x;
  __syncthreads();
  int add = 0;
  for (int w = 0; w < (threadIdx.x >> 6); ++w) add += wsum[w];
  int incl = x + add;
  if (i < NN) tmp[i] = incl - v;
  if (threadIdx.x == 255) bsum[blockIdx.x] = incl;
}

// single-wave chunked shuffle scan over NB block sums
__global__ void k_scan2(const int* __restrict__ bsum, int* __restrict__ boff) {
  int lane = threadIdx.x;  // 64 threads
  int run = 0;
  for (int b0 = 0; b0 < NB; b0 += 64) {
    int i = b0 + lane;
    int v = (i < NB) ? bsum[i] : 0;
    int x = v;
#pragma unroll
    for (int d = 1; d < 64; d <<= 1) {
      int y = __shfl_up(x, d);
      if (lane >= d) x += y;
    }
    if (i < NB) boff[i] = run + x - v;
    run += __shfl(x, 63);
  }
}

__global__ __launch_bounds__(256) void k_scan3(const int* __restrict__ deg, int* __restrict__ tmp,
                                               const int* __restrict__ boff, int* __restrict__ rs,
                                               float* __restrict__ dinv) {
  int i = blockIdx.x * 256 + threadIdx.x;
  if (i < NN) {
    int v = tmp[i] + boff[blockIdx.x];
    rs[i] = v;
    tmp[i] = v;  // becomes the atomic cursor for k_fill
    dinv[i] = rsqrtf((float)(deg[i] + 1));
  }
  if (i == 0) rs[NN] = NE;
}

// packed CSR payload: lo = src | (d<<17) ; hi = (d>>15) | (eid<<2)   (src,d 17b; eid 21b)
__global__ __launch_bounds__(256) void k_fill(const int* __restrict__ src, const int* __restrict__ dst,
                                              int* __restrict__ cursor, uint2* __restrict__ sde) {
  int e = blockIdx.x * 256 + threadIdx.x;
  if (e < NE) {
    int d = dst[e];
    int s = src[e];
    int p = atomicAdd(&cursor[d], 1);
    unsigned int lo = (unsigned int)s | ((unsigned int)d << 17);
    unsigned int hi = ((unsigned int)d >> 15) | ((unsigned int)e << 2);
    sde[p] = make_uint2(lo, hi);
  }
}

// ---------------- weight prep: fp32 [128][128] views -> bf16 B-fragment layout ----------------
// frag idx within matrix: ((f*4+t)*64+lane)*8+u  <->  n=f*16+(lane&15), k=t*32+(lane>>4)*8+u
// m=0: W1, m=1: W2, m=2: Wm1 rows 0..127, m=3: Wm1 rows 128..255
__global__ __launch_bounds__(256) void k_prep(const float* __restrict__ W1, const float* __restrict__ W2,
                                              const float* __restrict__ Wm1, unsigned short* __restrict__ Bp) {
  int gid = blockIdx.x * 256 + threadIdx.x;  // 0..65535
  int idx = gid & 16383;
  int m = gid >> 14;
  int u = idx & 7;
  int lane = (idx >> 3) & 63;
  int ft = idx >> 9;
  int t = ft & 3, f = ft >> 2;
  int n = f * 16 + (lane & 15);
  int k = t * 32 + (lane >> 4) * 8 + u;
  const float* Wsrc = (m == 0) ? W1 : (m == 1) ? W2 : Wm1;
  int krow = (m == 3) ? (k + 128) : k;
  Bp[gid] = f2bf(Wsrc[(size_t)krow * 128 + n]);
}

// ---------------- MFMA GEMM, bf16 A: Y = scale[r]? * (A @ W), K=N=128 ----------------
__global__ __launch_bounds__(256) void k_gemm_mfma(const unsigned short* __restrict__ A,
                                                   const unsigned short* __restrict__ Bp,
                                                   unsigned short* __restrict__ Y,
                                                   const float* __restrict__ scale, int nrows) {
  __shared__ unsigned short BL[16384];
  {
    const uint4* gp = (const uint4*)Bp;
    uint4* sp = (uint4*)BL;
#pragma unroll
    for (int i = 0; i < 8; ++i) sp[threadIdx.x + i * 256] = gp[threadIdx.x + i * 256];
  }
  __syncthreads();

  const int w = threadIdx.x >> 6, lane = threadIdx.x & 63;
  const int r = lane & 15, g = lane >> 4;
  const int rowbase = blockIdx.x * 64 + w * 16;
  const int arow = rowbase + r;

  bf16x8 av[4];
  if (arow < nrows) {
#pragma unroll
    for (int t = 0; t < 4; ++t) av[t] = *(const bf16x8*)(A + (size_t)arow * 128 + g * 8 + t * 32);
  } else {
#pragma unroll
    for (int t = 0; t < 4; ++t) av[t] = (bf16x8){0, 0, 0, 0, 0, 0, 0, 0};
  }

  f32x4 acc[8];
#pragma unroll
  for (int f = 0; f < 8; ++f) acc[f] = (f32x4){0.f, 0.f, 0.f, 0.f};

#pragma unroll
  for (int f = 0; f < 8; ++f)
#pragma unroll
    for (int t = 0; t < 4; ++t) {
      bf16x8 bv = *(const bf16x8*)(&BL[(((f << 2) | t) << 9) | (lane << 3)]);
      acc[f] = __builtin_amdgcn_mfma_f32_16x16x32_bf16(av[t], bv, acc[f], 0, 0, 0);
    }

#pragma unroll
  for (int j = 0; j < 4; ++j) {
    int row = rowbase + g * 4 + j;
    if (row < nrows) {
      float sc = scale ? scale[row] : 1.f;
#pragma unroll
      for (int f = 0; f < 8; ++f) Y[(size_t)row * 128 + f * 16 + r] = f2bf(acc[f][j] * sc);
    }
  }
}

// ---------------- MFMA GEMM, fp32 A (converts on the fly) ----------------
__global__ __launch_bounds__(256) void k_gemm_mfma_f32(const float* __restrict__ A,
                                                       const unsigned short* __restrict__ Bp,
                                                       unsigned short* __restrict__ Y,
                                                       const float* __restrict__ scale, int nrows) {
  __shared__ unsigned short BL[16384];
  {
    const uint4* gp = (const uint4*)Bp;
    uint4* sp = (uint4*)BL;
#pragma unroll
    for (int i = 0; i < 8; ++i) sp[threadIdx.x + i * 256] = gp[threadIdx.x + i * 256];
  }
  __syncthreads();

  const int w = threadIdx.x >> 6, lane = threadIdx.x & 63;
  const int r = lane & 15, g = lane >> 4;
  const int rowbase = blockIdx.x * 64 + w * 16;
  const int arow = rowbase + r;

  bf16x8 av[4];
  if (arow < nrows) {
#pragma unroll
    for (int t = 0; t < 4; ++t) {
      float4 a0 = *(const float4*)(A + (size_t)arow * 128 + g * 8 + t * 32);
      float4 a1 = *(const float4*)(A + (size_t)arow * 128 + g * 8 + t * 32 + 4);
      bf16x8 pk;
      pk[0] = (short)f2bf(a0.x); pk[1] = (short)f2bf(a0.y);
      pk[2] = (short)f2bf(a0.z); pk[3] = (short)f2bf(a0.w);
      pk[4] = (short)f2bf(a1.x); pk[5] = (short)f2bf(a1.y);
      pk[6] = (short)f2bf(a1.z); pk[7] = (short)f2bf(a1.w);
      av[t] = pk;
    }
  } else {
#pragma unroll
    for (int t = 0; t < 4; ++t) av[t] = (bf16x8){0, 0, 0, 0, 0, 0, 0, 0};
  }

  f32x4 acc[8];
#pragma unroll
  for (int f = 0; f < 8; ++f) acc[f] = (f32x4){0.f, 0.f, 0.f, 0.f};

#pragma unroll
  for (int f = 0; f < 8; ++f)
#pragma unroll
    for (int t = 0; t < 4; ++t) {
      bf16x8 bv = *(const bf16x8*)(&BL[(((f << 2) | t) << 9) | (lane << 3)]);
      acc[f] = __builtin_amdgcn_mfma_f32_16x16x32_bf16(av[t], bv, acc[f], 0, 0, 0);
    }

#pragma unroll
  for (int j = 0; j < 4; ++j) {
    int row = rowbase + g * 4 + j;
    if (row < nrows) {
      float sc = scale ? scale[row] : 1.f;
#pragma unroll
      for (int f = 0; f < 8; ++f) Y[(size_t)row * 128 + f * 16 + r] = f2bf(acc[f][j] * sc);
    }
  }
}

// ---------------- dual MFMA GEMM: U = A@Wm1t, V = A@Wm1b (A read once) ----------------
// 512 threads / 8 waves, 128 rows/block, both B matrices in 64KB LDS -> 2 blocks/CU.
__global__ __launch_bounds__(512) void k_gemm_dual(const unsigned short* __restrict__ A,
                                                   const unsigned short* __restrict__ Bp2,
                                                   unsigned short* __restrict__ U,
                                                   unsigned short* __restrict__ V, int nrows) {
  __shared__ unsigned short BL[32768];
  {
    const uint4* gp = (const uint4*)Bp2;
    uint4* sp = (uint4*)BL;
#pragma unroll
    for (int i = 0; i < 8; ++i) sp[threadIdx.x + i * 512] = gp[threadIdx.x + i * 512];
  }
  __syncthreads();

  const int w = threadIdx.x >> 6, lane = threadIdx.x & 63;
  const int r = lane & 15, g = lane >> 4;
  const int rowbase = blockIdx.x * 128 + w * 16;
  const int arow = rowbase + r;

  bf16x8 av[4];
  if (arow < nrows) {
#pragma unroll
    for (int t = 0; t < 4; ++t) av[t] = *(const bf16x8*)(A + (size_t)arow * 128 + g * 8 + t * 32);
  } else {
#pragma unroll
    for (int t = 0; t < 4; ++t) av[t] = (bf16x8){0, 0, 0, 0, 0, 0, 0, 0};
  }

  f32x4 accU[8], accV[8];
#pragma unroll
  for (int f = 0; f < 8; ++f) {
    accU[f] = (f32x4){0.f, 0.f, 0.f, 0.f};
    accV[f] = (f32x4){0.f, 0.f, 0.f, 0.f};
  }

#pragma unroll
  for (int f = 0; f < 8; ++f)
#pragma unroll
    for (int t = 0; t < 4; ++t) {
      bf16x8 bu = *(const bf16x8*)(&BL[(((f << 2) | t) << 9) | (lane << 3)]);
      bf16x8 bv = *(const bf16x8*)(&BL[16384 + ((((f << 2) | t) << 9) | (lane << 3))]);
      accU[f] = __builtin_amdgcn_mfma_f32_16x16x32_bf16(av[t], bu, accU[f], 0, 0, 0);
      accV[f] = __builtin_amdgcn_mfma_f32_16x16x32_bf16(av[t], bv, accV[f], 0, 0, 0);
    }

#pragma unroll
  for (int j = 0; j < 4; ++j) {
    int row = rowbase + g * 4 + j;
    if (row < nrows) {
#pragma unroll
      for (int f = 0; f < 8; ++f) {
        U[(size_t)row * 128 + f * 16 + r] = f2bf(accU[f][j]);
        V[(size_t)row * 128 + f * 16 + r] = f2bf(accV[f][j]);
      }
    }
  }
}

// ---------------- fused aggregate (T pre-scaled by dinv[row]):
// out[d] = relu(dinv[d]*(T'[d] + sum_s T'[s]) + b), bf16 out
__global__ __launch_bounds__(256) void k_agg(const unsigned short* __restrict__ T,
                                             const int* __restrict__ rs, const uint2* __restrict__ sde,
                                             const float* __restrict__ dinv, const float* __restrict__ bias,
                                             unsigned short* __restrict__ outB) {
  int node = blockIdx.x * 4 + (threadIdx.x >> 6);
  if (node >= NN) return;
  int lane = threadIdx.x & 63;
  int beg = rs[node], end = rs[node + 1];
  float dn = dinv[node];

  unsigned int sv = *(const unsigned int*)(T + (size_t)node * 128 + lane * 2);
  float ax = bf2f((unsigned short)(sv & 0xffff));
  float ay = bf2f((unsigned short)(sv >> 16));
  float bx = 0.f, by = 0.f;

  for (int j0 = beg; j0 < end; j0 += 64) {
    int sl = (j0 + lane < end) ? (int)(sde[j0 + lane].x & 0x1FFFFu) : 0;
    int n = end - j0;
    if (n > 64) n = 64;
    int c = 0;
    for (; c + 2 <= n; c += 2) {
      int s0 = __builtin_amdgcn_readlane(sl, c);
      int s1 = __builtin_amdgcn_readlane(sl, c + 1);
      unsigned int h0 = *(const unsigned int*)(T + (size_t)s0 * 128 + lane * 2);
      unsigned int h1 = *(const unsigned int*)(T + (size_t)s1 * 128 + lane * 2);
      ax += bf2f((unsigned short)(h0 & 0xffff));
      ay += bf2f((unsigned short)(h0 >> 16));
      bx += bf2f((unsigned short)(h1 & 0xffff));
      by += bf2f((unsigned short)(h1 >> 16));
    }
    if (c < n) {
      int s0 = __builtin_amdgcn_readlane(sl, c);
      unsigned int h0 = *(const unsigned int*)(T + (size_t)s0 * 128 + lane * 2);
      ax += bf2f((unsigned short)(h0 & 0xffff));
      ay += bf2f((unsigned short)(h0 >> 16));
    }
  }
  ax += bx;
  ay += by;

  float2 bb = *(const float2*)(bias + lane * 2);
  float ox = fmaxf(fmaf(dn, ax, bb.x), 0.f);
  float oy = fmaxf(fmaf(dn, ay, bb.y), 0.f);
  unsigned int pv = (unsigned int)f2bf(ox) | ((unsigned int)f2bf(oy) << 16);
  *(unsigned int*)(outB + (size_t)node * 128 + lane * 2) = pv;
}

// ---------------- edge epilogue, batched LDS-transpose reduce ----------------
__global__ __launch_bounds__(256) void k_edge(const unsigned short* __restrict__ u,
                                              const unsigned short* __restrict__ v,
                                              const uint2* __restrict__ sde,
                                              const float* __restrict__ bm1, const float* __restrict__ Wm2,
                                              const float* __restrict__ bm2, float* __restrict__ out) {
  __shared__ float red[4][32 * 65];
  const int w = threadIdx.x >> 6;
  const int lane = threadIdx.x & 63;
  float* __restrict__ myred = &red[w][0];

  const int bat = blockIdx.x * 4 + w;  // < 25000 (NE = 64*25000 exactly)
  const int jb = bat * 64;

  float2 bmv = *(const float2*)(bm1 + lane * 2);
  float2 w2 = *(const float2*)(Wm2 + lane * 2);
  const float b2 = bm2[0];

  const uint2 ev = sde[jb + lane];  // coalesced per-lane packed load

  int cur = -1;
  float vb0 = 0.f, vb1 = 0.f;

#pragma unroll
  for (int h2 = 0; h2 < 2; ++h2) {
#pragma unroll 8
    for (int c = 0; c < 32; ++c) {
      int idx = h2 * 32 + c;
      unsigned int lo = (unsigned int)__builtin_amdgcn_readlane((int)ev.x, idx);
      unsigned int hi = (unsigned int)__builtin_amdgcn_readlane((int)ev.y, idx);
      int s = (int)(lo & 0x1FFFFu);
      int d = (int)((lo >> 17) | ((hi & 3u) << 15));
      unsigned int uu = *(const unsigned int*)(u + (size_t)s * 128 + lane * 2);
      if (d != cur) {
        unsigned int vv = *(const unsigned int*)(v + (size_t)d * 128 + lane * 2);
        vb0 = bf2f((unsigned short)(vv & 0xffff)) + bmv.x;
        vb1 = bf2f((unsigned short)(vv >> 16)) + bmv.y;
        cur = d;
      }
      float z0 = fmaxf(bf2f((unsigned short)(uu & 0xffff)) + vb0, 0.f);
      float z1 = fmaxf(bf2f((unsigned short)(uu >> 16)) + vb1, 0.f);
      myred[c * 65 + lane] = fmaf(z0, w2.x, z1 * w2.y);
    }
    __syncthreads();

    int cr = lane & 31, hh = lane >> 5;
    const float* row = &myred[cr * 65 + hh * 32];
    float s0 = 0.f, s1 = 0.f;
#pragma unroll
    for (int k = 0; k < 32; k += 2) {
      s0 += row[k];
      s1 += row[k + 1];
    }
    float s = s0 + s1;
    s += __shfl_xor(s, 32);
    float sg = 1.f / (1.f + __expf(-(s + b2)));
    unsigned int hi2 = (unsigned int)__shfl((int)ev.y, h2 * 32 + cr);
    int eid = (int)(hi2 >> 2);
    if (hh == 0) out[eid] = sg;
    __syncthreads();
  }
}

// ---------------- launch ----------------
extern "C" void kernel_launch(void* const* d_in, const int* in_sizes, int n_in,
                              void* d_out, int out_size, void* d_ws, size_t ws_size,
                              hipStream_t stream) {
  const float* x   = (const float*)d_in[0];
  const int* ei    = (const int*)d_in[1];
  const float* W1  = (const float*)d_in[2];
  const float* b1  = (const float*)d_in[3];
  const float* W2  = (const float*)d_in[4];
  const float* b2  = (const float*)d_in[5];
  const float* Wm1 = (const float*)d_in[6];
  const float* bm1 = (const float*)d_in[7];
  const float* Wm2 = (const float*)d_in[8];
  const float* bm2 = (const float*)d_in[9];
  float* out = (float*)d_out;

  const int* src = ei;
  const int* dst = ei + NE;

  // workspace layout (high-water 92,708,864 B; round-1 proved ws_size >= 102.8 MB)
  char* ws = (char*)d_ws;
  int*   deg    = (int*)(ws + 0x000000);   // 400 KB
  int*   rs     = (int*)(ws + 0x080000);   // 400 KB (+4)
  int*   cursor = (int*)(ws + 0x100000);   // 400 KB
  float* dinv   = (float*)(ws + 0x180000); // 400 KB
  int*   bsum   = (int*)(ws + 0x200000);
  int*   boff   = (int*)(ws + 0x210000);
  unsigned short* Bp = (unsigned short*)(ws + 0x220000);  // 128 KB -> ends 0x240000
  uint2* sde    = (uint2*)(ws + 0x240000);  // 12.8 MB -> ends 15,159,296
  unsigned short* bufT = (unsigned short*)(ws + 0xE80000);   // 15,204,352 + 25.6MB = 40,804,352
  unsigned short* hbuf = (unsigned short*)(ws + 0x2700000);  // 40,894,464 + 25.6MB = 66,494,464
  unsigned short* vbuf = (unsigned short*)(ws + 0x4000000);  // 67,108,864 + 25.6MB = 92,708,864
  unsigned short* ubuf = bufT;

  const int gN = NB;
  const int gE = (NE + 255) / 256;
  const int gRow = (NN + 63) / 64;     // 1563
  const int gDual = (NN + 127) / 128;  // 782
  const int gAgg = (NN + 3) / 4;
  const int gEdge = 25000 / 4;

  // CSR build + weight prep
  k_zero<<<gN, 256, 0, stream>>>(deg);
  k_hist<<<gE, 256, 0, stream>>>(dst, deg);
  k_scan1<<<gN, 256, 0, stream>>>(deg, cursor, bsum);
  k_scan2<<<1, 64, 0, stream>>>(bsum, boff);
  k_scan3<<<gN, 256, 0, stream>>>(deg, cursor, boff, rs, dinv);
  k_fill<<<gE, 256, 0, stream>>>(src, dst, cursor, sde);
  k_prep<<<256, 256, 0, stream>>>(W1, W2, Wm1, Bp);

  // layer 1: T1' = dinv*(x@W1) (bf16, MFMA); h1 = agg (bf16)
  k_gemm_mfma_f32<<<gRow, 256, 0, stream>>>(x, Bp, bufT, dinv, NN);
  k_agg<<<gAgg, 256, 0, stream>>>(bufT, rs, sde, dinv, b1, hbuf);

  // layer 2: T2' = dinv*(h1@W2) (bf16, MFMA); h2 = agg (bf16)
  k_gemm_mfma<<<gRow, 256, 0, stream>>>(hbuf, Bp + 16384, bufT, dinv, NN);
  k_agg<<<gAgg, 256, 0, stream>>>(bufT, rs, sde, dinv, b2, hbuf);

  // u = h2 @ Wm1_top, v = h2 @ Wm1_bot (fused dual MFMA)
  k_gemm_dual<<<gDual, 512, 0, stream>>>(hbuf, Bp + 2 * 16384, ubuf, vbuf, NN);

  // edge epilogue
  k_edge<<<gEdge, 256, 0, stream>>>(ubuf, vbuf, sde, bm1, Wm2, bm2, out);
}

// Round 9
// 457.084 us; speedup vs baseline: 2.3496x; 1.1112x over previous
//
#include <hip/hip_runtime.h>
#include <math.h>

#define NN 100000
#define NE 1600000
#define NB 391    // ceil(NN/256)
#define PART 12500  // NN/8 nodes per XCD partition

typedef __attribute__((ext_vector_type(8))) short bf16x8;
typedef __attribute__((ext_vector_type(4))) float f32x4;

__device__ inline unsigned short f2bf(float f) {
  unsigned int u = __float_as_uint(f);
  u = u + 0x7fffu + ((u >> 16) & 1u);
  return (unsigned short)(u >> 16);
}
__device__ inline float bf2f(unsigned short h) {
  return __uint_as_float(((unsigned int)h) << 16);
}

// ---------------- CSR build ----------------
__global__ __launch_bounds__(256) void k_zero(int* __restrict__ deg) {
  int i = blockIdx.x * 256 + threadIdx.x;
  if (i < NN) deg[i] = 0;
}

// XCD-partitioned histogram: block b (xcd-class b&7) handles chunk b>>3,
// counts only dsts in its partition -> deg lines stay in one XCD's L2.
__global__ __launch_bounds__(256) void k_hist(const int* __restrict__ dst, int* __restrict__ deg) {
  int b = blockIdx.x;                       // 0..49999
  int xcd = b & 7;
  int e = (b >> 3) * 256 + threadIdx.x;     // 6250*256 == NE exactly
  int d = dst[e];
  if ((unsigned)(d - xcd * PART) < (unsigned)PART) atomicAdd(&deg[d], 1);
}

__global__ __launch_bounds__(256) void k_scan1(const int* __restrict__ deg, int* __restrict__ tmp,
                                               int* __restrict__ bsum) {
  __shared__ int wsum[4];
  int i = blockIdx.x * 256 + threadIdx.x;
  int v = (i < NN) ? deg[i] : 0;
  int x = v;
#pragma unroll
  for (int d = 1; d < 64; d <<= 1) {
    int y = __shfl_up(x, d);
    if ((threadIdx.x & 63) >= d) x += y;
  }
  if ((threadIdx.x & 63) == 63) wsum[threadIdx.x >> 6] = x;
  __syncthreads();
  int add = 0;
  for (int w = 0; w < (threadIdx.x >> 6); ++w) add += wsum[w];
  int incl = x + add;
  if (i < NN) tmp[i] = incl - v;
  if (threadIdx.x == 255) bsum[blockIdx.x] = incl;
}

// single-wave chunked shuffle scan over NB block sums
__global__ void k_scan2(const int* __restrict__ bsum, int* __restrict__ boff) {
  int lane = threadIdx.x;  // 64 threads
  int run = 0;
  for (int b0 = 0; b0 < NB; b0 += 64) {
    int i = b0 + lane;
    int v = (i < NB) ? bsum[i] : 0;
    int x = v;
#pragma unroll
    for (int d = 1; d < 64; d <<= 1) {
      int y = __shfl_up(x, d);
      if (lane >= d) x += y;
    }
    if (i < NB) boff[i] = run + x - v;
    run += __shfl(x, 63);
  }
}

__global__ __launch_bounds__(256) void k_scan3(const int* __restrict__ deg, int* __restrict__ tmp,
                                               const int* __restrict__ boff, int* __restrict__ rs,
                                               float* __restrict__ dinv) {
  int i = blockIdx.x * 256 + threadIdx.x;
  if (i < NN) {
    int v = tmp[i] + boff[blockIdx.x];
    rs[i] = v;
    tmp[i] = v;  // becomes the atomic cursor for k_fill
    dinv[i] = rsqrtf((float)(deg[i] + 1));
  }
  if (i == 0) rs[NN] = NE;
}

// XCD-partitioned fill. packed payload: lo = src | (d<<17) ; hi = (d>>15) | (eid<<2)
__global__ __launch_bounds__(256) void k_fill(const int* __restrict__ src, const int* __restrict__ dst,
                                              int* __restrict__ cursor, uint2* __restrict__ sde) {
  int b = blockIdx.x;                       // 0..49999
  int xcd = b & 7;
  int e = (b >> 3) * 256 + threadIdx.x;     // < NE exactly
  int d = dst[e];
  int s = src[e];
  if ((unsigned)(d - xcd * PART) < (unsigned)PART) {
    int p = atomicAdd(&cursor[d], 1);
    unsigned int lo = (unsigned int)s | ((unsigned int)d << 17);
    unsigned int hi = ((unsigned int)d >> 15) | ((unsigned int)e << 2);
    sde[p] = make_uint2(lo, hi);
  }
}

// ---------------- weight prep: fp32 [128][128] views -> bf16 B-fragment layout ----------------
// frag idx within matrix: ((f*4+t)*64+lane)*8+u  <->  n=f*16+(lane&15), k=t*32+(lane>>4)*8+u
// m=0: W1, m=1: W2, m=2: Wm1 rows 0..127, m=3: Wm1 rows 128..255
__global__ __launch_bounds__(256) void k_prep(const float* __restrict__ W1, const float* __restrict__ W2,
                                              const float* __restrict__ Wm1, unsigned short* __restrict__ Bp) {
  int gid = blockIdx.x * 256 + threadIdx.x;  // 0..65535
  int idx = gid & 16383;
  int m = gid >> 14;
  int u = idx & 7;
  int lane = (idx >> 3) & 63;
  int ft = idx >> 9;
  int t = ft & 3, f = ft >> 2;
  int n = f * 16 + (lane & 15);
  int k = t * 32 + (lane >> 4) * 8 + u;
  const float* Wsrc = (m == 0) ? W1 : (m == 1) ? W2 : Wm1;
  int krow = (m == 3) ? (k + 128) : k;
  Bp[gid] = f2bf(Wsrc[(size_t)krow * 128 + n]);
}

// ---------------- MFMA GEMM, bf16 A: Y = scale[r]? * (A @ W), K=N=128 ----------------
__global__ __launch_bounds__(256) void k_gemm_mfma(const unsigned short* __restrict__ A,
                                                   const unsigned short* __restrict__ Bp,
                                                   unsigned short* __restrict__ Y,
                                                   const float* __restrict__ scale, int nrows) {
  __shared__ unsigned short BL[16384];
  {
    const uint4* gp = (const uint4*)Bp;
    uint4* sp = (uint4*)BL;
#pragma unroll
    for (int i = 0; i < 8; ++i) sp[threadIdx.x + i * 256] = gp[threadIdx.x + i * 256];
  }
  __syncthreads();

  const int w = threadIdx.x >> 6, lane = threadIdx.x & 63;
  const int r = lane & 15, g = lane >> 4;
  const int rowbase = blockIdx.x * 64 + w * 16;
  const int arow = rowbase + r;

  bf16x8 av[4];
  if (arow < nrows) {
#pragma unroll
    for (int t = 0; t < 4; ++t) av[t] = *(const bf16x8*)(A + (size_t)arow * 128 + g * 8 + t * 32);
  } else {
#pragma unroll
    for (int t = 0; t < 4; ++t) av[t] = (bf16x8){0, 0, 0, 0, 0, 0, 0, 0};
  }

  f32x4 acc[8];
#pragma unroll
  for (int f = 0; f < 8; ++f) acc[f] = (f32x4){0.f, 0.f, 0.f, 0.f};

#pragma unroll
  for (int f = 0; f < 8; ++f)
#pragma unroll
    for (int t = 0; t < 4; ++t) {
      bf16x8 bv = *(const bf16x8*)(&BL[(((f << 2) | t) << 9) | (lane << 3)]);
      acc[f] = __builtin_amdgcn_mfma_f32_16x16x32_bf16(av[t], bv, acc[f], 0, 0, 0);
    }

#pragma unroll
  for (int j = 0; j < 4; ++j) {
    int row = rowbase + g * 4 + j;
    if (row < nrows) {
      float sc = scale ? scale[row] : 1.f;
#pragma unroll
      for (int f = 0; f < 8; ++f) Y[(size_t)row * 128 + f * 16 + r] = f2bf(acc[f][j] * sc);
    }
  }
}

// ---------------- MFMA GEMM, fp32 A (converts on the fly) ----------------
__global__ __launch_bounds__(256) void k_gemm_mfma_f32(const float* __restrict__ A,
                                                       const unsigned short* __restrict__ Bp,
                                                       unsigned short* __restrict__ Y,
                                                       const float* __restrict__ scale, int nrows) {
  __shared__ unsigned short BL[16384];
  {
    const uint4* gp = (const uint4*)Bp;
    uint4* sp = (uint4*)BL;
#pragma unroll
    for (int i = 0; i < 8; ++i) sp[threadIdx.x + i * 256] = gp[threadIdx.x + i * 256];
  }
  __syncthreads();

  const int w = threadIdx.x >> 6, lane = threadIdx.x & 63;
  const int r = lane & 15, g = lane >> 4;
  const int rowbase = blockIdx.x * 64 + w * 16;
  const int arow = rowbase + r;

  bf16x8 av[4];
  if (arow < nrows) {
#pragma unroll
    for (int t = 0; t < 4; ++t) {
      float4 a0 = *(const float4*)(A + (size_t)arow * 128 + g * 8 + t * 32);
      float4 a1 = *(const float4*)(A + (size_t)arow * 128 + g * 8 + t * 32 + 4);
      bf16x8 pk;
      pk[0] = (short)f2bf(a0.x); pk[1] = (short)f2bf(a0.y);
      pk[2] = (short)f2bf(a0.z); pk[3] = (short)f2bf(a0.w);
      pk[4] = (short)f2bf(a1.x); pk[5] = (short)f2bf(a1.y);
      pk[6] = (short)f2bf(a1.z); pk[7] = (short)f2bf(a1.w);
      av[t] = pk;
    }
  } else {
#pragma unroll
    for (int t = 0; t < 4; ++t) av[t] = (bf16x8){0, 0, 0, 0, 0, 0, 0, 0};
  }

  f32x4 acc[8];
#pragma unroll
  for (int f = 0; f < 8; ++f) acc[f] = (f32x4){0.f, 0.f, 0.f, 0.f};

#pragma unroll
  for (int f = 0; f < 8; ++f)
#pragma unroll
    for (int t = 0; t < 4; ++t) {
      bf16x8 bv = *(const bf16x8*)(&BL[(((f << 2) | t) << 9) | (lane << 3)]);
      acc[f] = __builtin_amdgcn_mfma_f32_16x16x32_bf16(av[t], bv, acc[f], 0, 0, 0);
    }

#pragma unroll
  for (int j = 0; j < 4; ++j) {
    int row = rowbase + g * 4 + j;
    if (row < nrows) {
      float sc = scale ? scale[row] : 1.f;
#pragma unroll
      for (int f = 0; f < 8; ++f) Y[(size_t)row * 128 + f * 16 + r] = f2bf(acc[f][j] * sc);
    }
  }
}

// ---------------- dual MFMA GEMM: U = A@Wm1t, V = A@Wm1b (A read once) ----------------
__global__ __launch_bounds__(512) void k_gemm_dual(const unsigned short* __restrict__ A,
                                                   const unsigned short* __restrict__ Bp2,
                                                   unsigned short* __restrict__ U,
                                                   unsigned short* __restrict__ V, int nrows) {
  __shared__ unsigned short BL[32768];
  {
    const uint4* gp = (const uint4*)Bp2;
    uint4* sp = (uint4*)BL;
#pragma unroll
    for (int i = 0; i < 8; ++i) sp[threadIdx.x + i * 512] = gp[threadIdx.x + i * 512];
  }
  __syncthreads();

  const int w = threadIdx.x >> 6, lane = threadIdx.x & 63;
  const int r = lane & 15, g = lane >> 4;
  const int rowbase = blockIdx.x * 128 + w * 16;
  const int arow = rowbase + r;

  bf16x8 av[4];
  if (arow < nrows) {
#pragma unroll
    for (int t = 0; t < 4; ++t) av[t] = *(const bf16x8*)(A + (size_t)arow * 128 + g * 8 + t * 32);
  } else {
#pragma unroll
    for (int t = 0; t < 4; ++t) av[t] = (bf16x8){0, 0, 0, 0, 0, 0, 0, 0};
  }

  f32x4 accU[8], accV[8];
#pragma unroll
  for (int f = 0; f < 8; ++f) {
    accU[f] = (f32x4){0.f, 0.f, 0.f, 0.f};
    accV[f] = (f32x4){0.f, 0.f, 0.f, 0.f};
  }

#pragma unroll
  for (int f = 0; f < 8; ++f)
#pragma unroll
    for (int t = 0; t < 4; ++t) {
      bf16x8 bu = *(const bf16x8*)(&BL[(((f << 2) | t) << 9) | (lane << 3)]);
      bf16x8 bv = *(const bf16x8*)(&BL[16384 + ((((f << 2) | t) << 9) | (lane << 3))]);
      accU[f] = __builtin_amdgcn_mfma_f32_16x16x32_bf16(av[t], bu, accU[f], 0, 0, 0);
      accV[f] = __builtin_amdgcn_mfma_f32_16x16x32_bf16(av[t], bv, accV[f], 0, 0, 0);
    }

#pragma unroll
  for (int j = 0; j < 4; ++j) {
    int row = rowbase + g * 4 + j;
    if (row < nrows) {
#pragma unroll
      for (int f = 0; f < 8; ++f) {
        U[(size_t)row * 128 + f * 16 + r] = f2bf(accU[f][j]);
        V[(size_t)row * 128 + f * 16 + r] = f2bf(accV[f][j]);
      }
    }
  }
}

// ---------------- fused aggregate (T pre-scaled by dinv[row]):
// out[d] = relu(dinv[d]*(T'[d] + sum_s T'[s]) + b), bf16 out
__global__ __launch_bounds__(256) void k_agg(const unsigned short* __restrict__ T,
                                             const int* __restrict__ rs, const uint2* __restrict__ sde,
                                             const float* __restrict__ dinv, const float* __restrict__ bias,
                                             unsigned short* __restrict__ outB) {
  int node = blockIdx.x * 4 + (threadIdx.x >> 6);
  if (node >= NN) return;
  int lane = threadIdx.x & 63;
  int beg = rs[node], end = rs[node + 1];
  float dn = dinv[node];

  unsigned int sv = *(const unsigned int*)(T + (size_t)node * 128 + lane * 2);
  float ax = bf2f((unsigned short)(sv & 0xffff));
  float ay = bf2f((unsigned short)(sv >> 16));
  float bx = 0.f, by = 0.f;

  for (int j0 = beg; j0 < end; j0 += 64) {
    int sl = (j0 + lane < end) ? (int)(sde[j0 + lane].x & 0x1FFFFu) : 0;
    int n = end - j0;
    if (n > 64) n = 64;
    int c = 0;
    for (; c + 2 <= n; c += 2) {
      int s0 = __builtin_amdgcn_readlane(sl, c);
      int s1 = __builtin_amdgcn_readlane(sl, c + 1);
      unsigned int h0 = *(const unsigned int*)(T + (size_t)s0 * 128 + lane * 2);
      unsigned int h1 = *(const unsigned int*)(T + (size_t)s1 * 128 + lane * 2);
      ax += bf2f((unsigned short)(h0 & 0xffff));
      ay += bf2f((unsigned short)(h0 >> 16));
      bx += bf2f((unsigned short)(h1 & 0xffff));
      by += bf2f((unsigned short)(h1 >> 16));
    }
    if (c < n) {
      int s0 = __builtin_amdgcn_readlane(sl, c);
      unsigned int h0 = *(const unsigned int*)(T + (size_t)s0 * 128 + lane * 2);
      ax += bf2f((unsigned short)(h0 & 0xffff));
      ay += bf2f((unsigned short)(h0 >> 16));
    }
  }
  ax += bx;
  ay += by;

  float2 bb = *(const float2*)(bias + lane * 2);
  float ox = fmaxf(fmaf(dn, ax, bb.x), 0.f);
  float oy = fmaxf(fmaf(dn, ay, bb.y), 0.f);
  unsigned int pv = (unsigned int)f2bf(ox) | ((unsigned int)f2bf(oy) << 16);
  *(unsigned int*)(outB + (size_t)node * 128 + lane * 2) = pv;
}

// ---------------- edge epilogue, batched LDS-transpose reduce ----------------
__global__ __launch_bounds__(256) void k_edge(const unsigned short* __restrict__ u,
                                              const unsigned short* __restrict__ v,
                                              const uint2* __restrict__ sde,
                                              const float* __restrict__ bm1, const float* __restrict__ Wm2,
                                              const float* __restrict__ bm2, float* __restrict__ out) {
  __shared__ float red[4][32 * 65];
  const int w = threadIdx.x >> 6;
  const int lane = threadIdx.x & 63;
  float* __restrict__ myred = &red[w][0];

  const int bat = blockIdx.x * 4 + w;  // < 25000 (NE = 64*25000 exactly)
  const int jb = bat * 64;

  float2 bmv = *(const float2*)(bm1 + lane * 2);
  float2 w2 = *(const float2*)(Wm2 + lane * 2);
  const float b2 = bm2[0];

  const uint2 ev = sde[jb + lane];  // coalesced per-lane packed load

  int cur = -1;
  float vb0 = 0.f, vb1 = 0.f;

#pragma unroll
  for (int h2 = 0; h2 < 2; ++h2) {
#pragma unroll 8
    for (int c = 0; c < 32; ++c) {
      int idx = h2 * 32 + c;
      unsigned int lo = (unsigned int)__builtin_amdgcn_readlane((int)ev.x, idx);
      unsigned int hi = (unsigned int)__builtin_amdgcn_readlane((int)ev.y, idx);
      int s = (int)(lo & 0x1FFFFu);
      int d = (int)((lo >> 17) | ((hi & 3u) << 15));
      unsigned int uu = *(const unsigned int*)(u + (size_t)s * 128 + lane * 2);
      if (d != cur) {
        unsigned int vv = *(const unsigned int*)(v + (size_t)d * 128 + lane * 2);
        vb0 = bf2f((unsigned short)(vv & 0xffff)) + bmv.x;
        vb1 = bf2f((unsigned short)(vv >> 16)) + bmv.y;
        cur = d;
      }
      float z0 = fmaxf(bf2f((unsigned short)(uu & 0xffff)) + vb0, 0.f);
      float z1 = fmaxf(bf2f((unsigned short)(uu >> 16)) + vb1, 0.f);
      myred[c * 65 + lane] = fmaf(z0, w2.x, z1 * w2.y);
    }
    __syncthreads();

    int cr = lane & 31, hh = lane >> 5;
    const float* row = &myred[cr * 65 + hh * 32];
    float s0 = 0.f, s1 = 0.f;
#pragma unroll
    for (int k = 0; k < 32; k += 2) {
      s0 += row[k];
      s1 += row[k + 1];
    }
    float s = s0 + s1;
    s += __shfl_xor(s, 32);
    float sg = 1.f / (1.f + __expf(-(s + b2)));
    unsigned int hi2 = (unsigned int)__shfl((int)ev.y, h2 * 32 + cr);
    int eid = (int)(hi2 >> 2);
    if (hh == 0) out[eid] = sg;
    __syncthreads();
  }
}

// ---------------- launch ----------------
extern "C" void kernel_launch(void* const* d_in, const int* in_sizes, int n_in,
                              void* d_out, int out_size, void* d_ws, size_t ws_size,
                              hipStream_t stream) {
  const float* x   = (const float*)d_in[0];
  const int* ei    = (const int*)d_in[1];
  const float* W1  = (const float*)d_in[2];
  const float* b1  = (const float*)d_in[3];
  const float* W2  = (const float*)d_in[4];
  const float* b2  = (const float*)d_in[5];
  const float* Wm1 = (const float*)d_in[6];
  const float* bm1 = (const float*)d_in[7];
  const float* Wm2 = (const float*)d_in[8];
  const float* bm2 = (const float*)d_in[9];
  float* out = (float*)d_out;

  const int* src = ei;
  const int* dst = ei + NE;

  // workspace layout (high-water 92,708,864 B; round-1 proved ws_size >= 102.8 MB)
  char* ws = (char*)d_ws;
  int*   deg    = (int*)(ws + 0x000000);   // 400 KB
  int*   rs     = (int*)(ws + 0x080000);   // 400 KB (+4)
  int*   cursor = (int*)(ws + 0x100000);   // 400 KB
  float* dinv   = (float*)(ws + 0x180000); // 400 KB
  int*   bsum   = (int*)(ws + 0x200000);
  int*   boff   = (int*)(ws + 0x210000);
  unsigned short* Bp = (unsigned short*)(ws + 0x220000);  // 128 KB -> ends 0x240000
  uint2* sde    = (uint2*)(ws + 0x240000);  // 12.8 MB -> ends 15,159,296
  unsigned short* bufT = (unsigned short*)(ws + 0xE80000);   // 25.6 MB -> ends 40,804,352
  unsigned short* hbuf = (unsigned short*)(ws + 0x2700000);  // 25.6 MB -> ends 66,494,464
  unsigned short* vbuf = (unsigned short*)(ws + 0x4000000);  // 25.6 MB -> ends 92,708,864
  unsigned short* ubuf = bufT;

  const int gN = NB;
  const int gPart = (NE / 256) * 8;    // 50000: XCD-partitioned hist/fill
  const int gRow = (NN + 63) / 64;     // 1563
  const int gDual = (NN + 127) / 128;  // 782
  const int gAgg = (NN + 3) / 4;
  const int gEdge = 25000 / 4;

  // CSR build + weight prep
  k_zero<<<gN, 256, 0, stream>>>(deg);
  k_hist<<<gPart, 256, 0, stream>>>(dst, deg);
  k_scan1<<<gN, 256, 0, stream>>>(deg, cursor, bsum);
  k_scan2<<<1, 64, 0, stream>>>(bsum, boff);
  k_scan3<<<gN, 256, 0, stream>>>(deg, cursor, boff, rs, dinv);
  k_fill<<<gPart, 256, 0, stream>>>(src, dst, cursor, sde);
  k_prep<<<256, 256, 0, stream>>>(W1, W2, Wm1, Bp);

  // layer 1: T1' = dinv*(x@W1) (bf16, MFMA); h1 = agg (bf16)
  k_gemm_mfma_f32<<<gRow, 256, 0, stream>>>(x, Bp, bufT, dinv, NN);
  k_agg<<<gAgg, 256, 0, stream>>>(bufT, rs, sde, dinv, b1, hbuf);

  // layer 2: T2' = dinv*(h1@W2) (bf16, MFMA); h2 = agg (bf16)
  k_gemm_mfma<<<gRow, 256, 0, stream>>>(hbuf, Bp + 16384, bufT, dinv, NN);
  k_agg<<<gAgg, 256, 0, stream>>>(bufT, rs, sde, dinv, b2, hbuf);

  // u = h2 @ Wm1_top, v = h2 @ Wm1_bot (fused dual MFMA)
  k_gemm_dual<<<gDual, 512, 0, stream>>>(hbuf, Bp + 2 * 16384, ubuf, vbuf, NN);

  // edge epilogue
  k_edge<<<gEdge, 256, 0, stream>>>(ubuf, vbuf, sde, bm1, Wm2, bm2, out);
}

// Round 10
// 409.849 us; speedup vs baseline: 2.6204x; 1.1153x over previous
//
#include <hip/hip_runtime.h>
#include <math.h>

#define NN 100000
#define NE 1600000
#define NB 391    // ceil(NN/256)
#define PART 12500  // NN/8 nodes per XCD partition

typedef __attribute__((ext_vector_type(8))) short bf16x8;
typedef __attribute__((ext_vector_type(4))) float f32x4;

__device__ inline unsigned short f2bf(float f) {
  unsigned int u = __float_as_uint(f);
  u = u + 0x7fffu + ((u >> 16) & 1u);
  return (unsigned short)(u >> 16);
}
__device__ inline float bf2f(unsigned short h) {
  return __uint_as_float(((unsigned int)h) << 16);
}
// packed dword (2 bf16) -> 2 floats, 1 op each
__device__ inline void unpk(unsigned int w, float& a, float& b) {
  a = __uint_as_float(w << 16);
  b = __uint_as_float(w & 0xffff0000u);
}

// ---------------- CSR build ----------------
__global__ __launch_bounds__(256) void k_zero(int* __restrict__ deg) {
  int i = blockIdx.x * 256 + threadIdx.x;
  if (i < NN) deg[i] = 0;
}

// XCD-partitioned histogram: block b (class b&7) handles chunk b>>3.
__global__ __launch_bounds__(256) void k_hist(const int* __restrict__ dst, int* __restrict__ deg) {
  int b = blockIdx.x;                       // 0..49999
  int xcd = b & 7;
  int e = (b >> 3) * 256 + threadIdx.x;
  int d = dst[e];
  if ((unsigned)(d - xcd * PART) < (unsigned)PART) atomicAdd(&deg[d], 1);
}

__global__ __launch_bounds__(256) void k_scan1(const int* __restrict__ deg, int* __restrict__ tmp,
                                               int* __restrict__ bsum) {
  __shared__ int wsum[4];
  int i = blockIdx.x * 256 + threadIdx.x;
  int v = (i < NN) ? deg[i] : 0;
  int x = v;
#pragma unroll
  for (int d = 1; d < 64; d <<= 1) {
    int y = __shfl_up(x, d);
    if ((threadIdx.x & 63) >= d) x += y;
  }
  if ((threadIdx.x & 63) == 63) wsum[threadIdx.x >> 6] = x;
  __syncthreads();
  int add = 0;
  for (int w = 0; w < (threadIdx.x >> 6); ++w) add += wsum[w];
  int incl = x + add;
  if (i < NN) tmp[i] = incl - v;
  if (threadIdx.x == 255) bsum[blockIdx.x] = incl;
}

// single-wave chunked shuffle scan over NB block sums
__global__ void k_scan2(const int* __restrict__ bsum, int* __restrict__ boff) {
  int lane = threadIdx.x;  // 64 threads
  int run = 0;
  for (int b0 = 0; b0 < NB; b0 += 64) {
    int i = b0 + lane;
    int v = (i < NB) ? bsum[i] : 0;
    int x = v;
#pragma unroll
    for (int d = 1; d < 64; d <<= 1) {
      int y = __shfl_up(x, d);
      if (lane >= d) x += y;
    }
    if (i < NB) boff[i] = run + x - v;
    run += __shfl(x, 63);
  }
}

__global__ __launch_bounds__(256) void k_scan3(const int* __restrict__ deg, int* __restrict__ tmp,
                                               const int* __restrict__ boff, int* __restrict__ rs,
                                               float* __restrict__ dinv) {
  int i = blockIdx.x * 256 + threadIdx.x;
  if (i < NN) {
    int v = tmp[i] + boff[blockIdx.x];
    rs[i] = v;
    tmp[i] = v;  // becomes the atomic cursor for k_fill
    dinv[i] = rsqrtf((float)(deg[i] + 1));
  }
  if (i == 0) rs[NN] = NE;
}

// XCD-partitioned fill. packed payload: lo = src | (d<<17) ; hi = (d>>15) | (eid<<2)
__global__ __launch_bounds__(256) void k_fill(const int* __restrict__ src, const int* __restrict__ dst,
                                              int* __restrict__ cursor, uint2* __restrict__ sde) {
  int b = blockIdx.x;
  int xcd = b & 7;
  int e = (b >> 3) * 256 + threadIdx.x;
  int d = dst[e];
  int s = src[e];
  if ((unsigned)(d - xcd * PART) < (unsigned)PART) {
    int p = atomicAdd(&cursor[d], 1);
    unsigned int lo = (unsigned int)s | ((unsigned int)d << 17);
    unsigned int hi = ((unsigned int)d >> 15) | ((unsigned int)e << 2);
    sde[p] = make_uint2(lo, hi);
  }
}

// ---------------- weight prep: fp32 [128][128] views -> bf16 B-fragment layout ----------------
__global__ __launch_bounds__(256) void k_prep(const float* __restrict__ W1, const float* __restrict__ W2,
                                              const float* __restrict__ Wm1, unsigned short* __restrict__ Bp) {
  int gid = blockIdx.x * 256 + threadIdx.x;  // 0..65535
  int idx = gid & 16383;
  int m = gid >> 14;
  int u = idx & 7;
  int lane = (idx >> 3) & 63;
  int ft = idx >> 9;
  int t = ft & 3, f = ft >> 2;
  int n = f * 16 + (lane & 15);
  int k = t * 32 + (lane >> 4) * 8 + u;
  const float* Wsrc = (m == 0) ? W1 : (m == 1) ? W2 : Wm1;
  int krow = (m == 3) ? (k + 128) : k;
  Bp[gid] = f2bf(Wsrc[(size_t)krow * 128 + n]);
}

// ---------------- MFMA GEMM, bf16 A ----------------
__global__ __launch_bounds__(256) void k_gemm_mfma(const unsigned short* __restrict__ A,
                                                   const unsigned short* __restrict__ Bp,
                                                   unsigned short* __restrict__ Y,
                                                   const float* __restrict__ scale, int nrows) {
  __shared__ unsigned short BL[16384];
  {
    const uint4* gp = (const uint4*)Bp;
    uint4* sp = (uint4*)BL;
#pragma unroll
    for (int i = 0; i < 8; ++i) sp[threadIdx.x + i * 256] = gp[threadIdx.x + i * 256];
  }
  __syncthreads();

  const int w = threadIdx.x >> 6, lane = threadIdx.x & 63;
  const int r = lane & 15, g = lane >> 4;
  const int rowbase = blockIdx.x * 64 + w * 16;
  const int arow = rowbase + r;

  bf16x8 av[4];
  if (arow < nrows) {
#pragma unroll
    for (int t = 0; t < 4; ++t) av[t] = *(const bf16x8*)(A + (size_t)arow * 128 + g * 8 + t * 32);
  } else {
#pragma unroll
    for (int t = 0; t < 4; ++t) av[t] = (bf16x8){0, 0, 0, 0, 0, 0, 0, 0};
  }

  f32x4 acc[8];
#pragma unroll
  for (int f = 0; f < 8; ++f) acc[f] = (f32x4){0.f, 0.f, 0.f, 0.f};

#pragma unroll
  for (int f = 0; f < 8; ++f)
#pragma unroll
    for (int t = 0; t < 4; ++t) {
      bf16x8 bv = *(const bf16x8*)(&BL[(((f << 2) | t) << 9) | (lane << 3)]);
      acc[f] = __builtin_amdgcn_mfma_f32_16x16x32_bf16(av[t], bv, acc[f], 0, 0, 0);
    }

#pragma unroll
  for (int j = 0; j < 4; ++j) {
    int row = rowbase + g * 4 + j;
    if (row < nrows) {
      float sc = scale ? scale[row] : 1.f;
#pragma unroll
      for (int f = 0; f < 8; ++f) Y[(size_t)row * 128 + f * 16 + r] = f2bf(acc[f][j] * sc);
    }
  }
}

// ---------------- MFMA GEMM, fp32 A (converts on the fly) ----------------
__global__ __launch_bounds__(256) void k_gemm_mfma_f32(const float* __restrict__ A,
                                                       const unsigned short* __restrict__ Bp,
                                                       unsigned short* __restrict__ Y,
                                                       const float* __restrict__ scale, int nrows) {
  __shared__ unsigned short BL[16384];
  {
    const uint4* gp = (const uint4*)Bp;
    uint4* sp = (uint4*)BL;
#pragma unroll
    for (int i = 0; i < 8; ++i) sp[threadIdx.x + i * 256] = gp[threadIdx.x + i * 256];
  }
  __syncthreads();

  const int w = threadIdx.x >> 6, lane = threadIdx.x & 63;
  const int r = lane & 15, g = lane >> 4;
  const int rowbase = blockIdx.x * 64 + w * 16;
  const int arow = rowbase + r;

  bf16x8 av[4];
  if (arow < nrows) {
#pragma unroll
    for (int t = 0; t < 4; ++t) {
      float4 a0 = *(const float4*)(A + (size_t)arow * 128 + g * 8 + t * 32);
      float4 a1 = *(const float4*)(A + (size_t)arow * 128 + g * 8 + t * 32 + 4);
      bf16x8 pk;
      pk[0] = (short)f2bf(a0.x); pk[1] = (short)f2bf(a0.y);
      pk[2] = (short)f2bf(a0.z); pk[3] = (short)f2bf(a0.w);
      pk[4] = (short)f2bf(a1.x); pk[5] = (short)f2bf(a1.y);
      pk[6] = (short)f2bf(a1.z); pk[7] = (short)f2bf(a1.w);
      av[t] = pk;
    }
  } else {
#pragma unroll
    for (int t = 0; t < 4; ++t) av[t] = (bf16x8){0, 0, 0, 0, 0, 0, 0, 0};
  }

  f32x4 acc[8];
#pragma unroll
  for (int f = 0; f < 8; ++f) acc[f] = (f32x4){0.f, 0.f, 0.f, 0.f};

#pragma unroll
  for (int f = 0; f < 8; ++f)
#pragma unroll
    for (int t = 0; t < 4; ++t) {
      bf16x8 bv = *(const bf16x8*)(&BL[(((f << 2) | t) << 9) | (lane << 3)]);
      acc[f] = __builtin_amdgcn_mfma_f32_16x16x32_bf16(av[t], bv, acc[f], 0, 0, 0);
    }

#pragma unroll
  for (int j = 0; j < 4; ++j) {
    int row = rowbase + g * 4 + j;
    if (row < nrows) {
      float sc = scale ? scale[row] : 1.f;
#pragma unroll
      for (int f = 0; f < 8; ++f) Y[(size_t)row * 128 + f * 16 + r] = f2bf(acc[f][j] * sc);
    }
  }
}

// ---------------- dual MFMA GEMM: U = A@Wm1t, V = A@Wm1b ----------------
__global__ __launch_bounds__(512) void k_gemm_dual(const unsigned short* __restrict__ A,
                                                   const unsigned short* __restrict__ Bp2,
                                                   unsigned short* __restrict__ U,
                                                   unsigned short* __restrict__ V, int nrows) {
  __shared__ unsigned short BL[32768];
  {
    const uint4* gp = (const uint4*)Bp2;
    uint4* sp = (uint4*)BL;
#pragma unroll
    for (int i = 0; i < 8; ++i) sp[threadIdx.x + i * 512] = gp[threadIdx.x + i * 512];
  }
  __syncthreads();

  const int w = threadIdx.x >> 6, lane = threadIdx.x & 63;
  const int r = lane & 15, g = lane >> 4;
  const int rowbase = blockIdx.x * 128 + w * 16;
  const int arow = rowbase + r;

  bf16x8 av[4];
  if (arow < nrows) {
#pragma unroll
    for (int t = 0; t < 4; ++t) av[t] = *(const bf16x8*)(A + (size_t)arow * 128 + g * 8 + t * 32);
  } else {
#pragma unroll
    for (int t = 0; t < 4; ++t) av[t] = (bf16x8){0, 0, 0, 0, 0, 0, 0, 0};
  }

  f32x4 accU[8], accV[8];
#pragma unroll
  for (int f = 0; f < 8; ++f) {
    accU[f] = (f32x4){0.f, 0.f, 0.f, 0.f};
    accV[f] = (f32x4){0.f, 0.f, 0.f, 0.f};
  }

#pragma unroll
  for (int f = 0; f < 8; ++f)
#pragma unroll
    for (int t = 0; t < 4; ++t) {
      bf16x8 bu = *(const bf16x8*)(&BL[(((f << 2) | t) << 9) | (lane << 3)]);
      bf16x8 bv = *(const bf16x8*)(&BL[16384 + ((((f << 2) | t) << 9) | (lane << 3))]);
      accU[f] = __builtin_amdgcn_mfma_f32_16x16x32_bf16(av[t], bu, accU[f], 0, 0, 0);
      accV[f] = __builtin_amdgcn_mfma_f32_16x16x32_bf16(av[t], bv, accV[f], 0, 0, 0);
    }

#pragma unroll
  for (int j = 0; j < 4; ++j) {
    int row = rowbase + g * 4 + j;
    if (row < nrows) {
#pragma unroll
      for (int f = 0; f < 8; ++f) {
        U[(size_t)row * 128 + f * 16 + r] = f2bf(accU[f][j]);
        V[(size_t)row * 128 + f * 16 + r] = f2bf(accV[f][j]);
      }
    }
  }
}

// ---------------- fused aggregate, 16B/lane quarter-wave gather ----------------
// out[d] = relu(dinv[d]*(T'[d] + sum_s T'[s]) + b), bf16 out.
// lane = (q = lane>>4, r = lane&15); lane covers cols r*8..r*8+7; quarter q takes edges 4c+q.
__global__ __launch_bounds__(256) void k_agg(const unsigned short* __restrict__ T,
                                             const int* __restrict__ rs, const uint2* __restrict__ sde,
                                             const float* __restrict__ dinv, const float* __restrict__ bias,
                                             unsigned short* __restrict__ outB) {
  int node = blockIdx.x * 4 + (threadIdx.x >> 6);
  if (node >= NN) return;
  int lane = threadIdx.x & 63;
  int q = lane >> 4, r = lane & 15;
  int beg = rs[node], end = rs[node + 1];
  float dn = dinv[node];

  float acc[8];
#pragma unroll
  for (int i = 0; i < 8; ++i) acc[i] = 0.f;

  for (int j0 = beg; j0 < end; j0 += 64) {
    int sl = (j0 + lane < end) ? (int)(sde[j0 + lane].x & 0x1FFFFu) : 0;
    int n = end - j0;
    if (n > 64) n = 64;
#pragma unroll 4
    for (int c = 0; c * 4 < n; ++c) {
      int idx = (c << 2) | q;
      int s = __shfl(sl, idx);
      if (idx < n) {
        uint4 hv = *(const uint4*)(T + (size_t)s * 128 + r * 8);
        float f0, f1, f2, f3, f4, f5, f6, f7;
        unpk(hv.x, f0, f1); unpk(hv.y, f2, f3);
        unpk(hv.z, f4, f5); unpk(hv.w, f6, f7);
        acc[0] += f0; acc[1] += f1; acc[2] += f2; acc[3] += f3;
        acc[4] += f4; acc[5] += f5; acc[6] += f6; acc[7] += f7;
      }
    }
  }

  // combine quarters
#pragma unroll
  for (int i = 0; i < 8; ++i) {
    acc[i] += __shfl_xor(acc[i], 16);
    acc[i] += __shfl_xor(acc[i], 32);
  }

  // self + bias + relu, pack, store (lanes q==0 only)
  uint4 sv = *(const uint4*)(T + (size_t)node * 128 + r * 8);
  float s0, s1, s2, s3, s4, s5, s6, s7;
  unpk(sv.x, s0, s1); unpk(sv.y, s2, s3);
  unpk(sv.z, s4, s5); unpk(sv.w, s6, s7);
  float4 ba = *(const float4*)(bias + r * 8);
  float4 bb = *(const float4*)(bias + r * 8 + 4);
  float o0 = fmaxf(fmaf(dn, acc[0] + s0, ba.x), 0.f);
  float o1 = fmaxf(fmaf(dn, acc[1] + s1, ba.y), 0.f);
  float o2 = fmaxf(fmaf(dn, acc[2] + s2, ba.z), 0.f);
  float o3 = fmaxf(fmaf(dn, acc[3] + s3, ba.w), 0.f);
  float o4 = fmaxf(fmaf(dn, acc[4] + s4, bb.x), 0.f);
  float o5 = fmaxf(fmaf(dn, acc[5] + s5, bb.y), 0.f);
  float o6 = fmaxf(fmaf(dn, acc[6] + s6, bb.z), 0.f);
  float o7 = fmaxf(fmaf(dn, acc[7] + s7, bb.w), 0.f);
  if (q == 0) {
    uint4 pv;
    pv.x = (unsigned int)f2bf(o0) | ((unsigned int)f2bf(o1) << 16);
    pv.y = (unsigned int)f2bf(o2) | ((unsigned int)f2bf(o3) << 16);
    pv.z = (unsigned int)f2bf(o4) | ((unsigned int)f2bf(o5) << 16);
    pv.w = (unsigned int)f2bf(o6) | ((unsigned int)f2bf(o7) << 16);
    *(uint4*)(outB + (size_t)node * 128 + r * 8) = pv;
  }
}

// ---------------- edge epilogue, 16B/lane quarter-wave gather + LDS reduce ----------------
// wave handles 64 CSR edges; iteration c: quarter q computes edge 4c+q, lane covers 8 cols.
__global__ __launch_bounds__(256) void k_edge(const unsigned short* __restrict__ u,
                                              const unsigned short* __restrict__ v,
                                              const uint2* __restrict__ sde,
                                              const float* __restrict__ bm1, const float* __restrict__ Wm2,
                                              const float* __restrict__ bm2, float* __restrict__ out) {
  __shared__ float red[4][16 * 65];
  const int w = threadIdx.x >> 6;
  const int lane = threadIdx.x & 63;
  const int q = lane >> 4, r = lane & 15;
  float* __restrict__ myred = &red[w][0];

  const int jb = (blockIdx.x * 4 + w) * 64;  // batch base (NE = 64*25000 exactly)

  float bmv[8], w2[8];
  {
    float4 a = *(const float4*)(bm1 + r * 8);
    float4 b = *(const float4*)(bm1 + r * 8 + 4);
    bmv[0] = a.x; bmv[1] = a.y; bmv[2] = a.z; bmv[3] = a.w;
    bmv[4] = b.x; bmv[5] = b.y; bmv[6] = b.z; bmv[7] = b.w;
    float4 c = *(const float4*)(Wm2 + r * 8);
    float4 d = *(const float4*)(Wm2 + r * 8 + 4);
    w2[0] = c.x; w2[1] = c.y; w2[2] = c.z; w2[3] = c.w;
    w2[4] = d.x; w2[5] = d.y; w2[6] = d.z; w2[7] = d.w;
  }
  const float b2 = bm2[0];

  const uint2 ev = sde[jb + lane];  // coalesced packed load (64 edges)
  const int sl = (int)(ev.x & 0x1FFFFu);
  const int dl = (int)((ev.x >> 17) | ((ev.y & 3u) << 15));

  int cur = -1;
  float vb[8];
#pragma unroll
  for (int i = 0; i < 8; ++i) vb[i] = 0.f;

#pragma unroll 4
  for (int c = 0; c < 16; ++c) {
    int idx = (c << 2) | q;
    int s = __shfl(sl, idx);
    int d = __shfl(dl, idx);
    uint4 uu = *(const uint4*)(u + (size_t)s * 128 + r * 8);
    if (d != cur) {
      uint4 vv = *(const uint4*)(v + (size_t)d * 128 + r * 8);
      float g0, g1, g2, g3, g4, g5, g6, g7;
      unpk(vv.x, g0, g1); unpk(vv.y, g2, g3);
      unpk(vv.z, g4, g5); unpk(vv.w, g6, g7);
      vb[0] = g0 + bmv[0]; vb[1] = g1 + bmv[1];
      vb[2] = g2 + bmv[2]; vb[3] = g3 + bmv[3];
      vb[4] = g4 + bmv[4]; vb[5] = g5 + bmv[5];
      vb[6] = g6 + bmv[6]; vb[7] = g7 + bmv[7];
      cur = d;
    }
    float f0, f1, f2, f3, f4, f5, f6, f7;
    unpk(uu.x, f0, f1); unpk(uu.y, f2, f3);
    unpk(uu.z, f4, f5); unpk(uu.w, f6, f7);
    float p = 0.f;
    p = fmaf(fmaxf(f0 + vb[0], 0.f), w2[0], p);
    p = fmaf(fmaxf(f1 + vb[1], 0.f), w2[1], p);
    p = fmaf(fmaxf(f2 + vb[2], 0.f), w2[2], p);
    p = fmaf(fmaxf(f3 + vb[3], 0.f), w2[3], p);
    p = fmaf(fmaxf(f4 + vb[4], 0.f), w2[4], p);
    p = fmaf(fmaxf(f5 + vb[5], 0.f), w2[5], p);
    p = fmaf(fmaxf(f6 + vb[6], 0.f), w2[6], p);
    p = fmaf(fmaxf(f7 + vb[7], 0.f), w2[7], p);
    myred[c * 65 + q * 16 + r] = p;  // partial for edge 4c+q, col-block r
  }
  __syncthreads();

  // lane L reduces edge L: 16 partials at red[L>>2][(L&3)*16 + k] (2-way bank alias)
  {
    const float* row = &myred[(lane >> 2) * 65 + (lane & 3) * 16];
    float s0 = 0.f, s1 = 0.f;
#pragma unroll
    for (int k = 0; k < 16; k += 2) {
      s0 += row[k];
      s1 += row[k + 1];
    }
    float logit = s0 + s1 + b2;
    int eid = (int)(ev.y >> 2);  // own lane's edge id
    out[eid] = 1.f / (1.f + __expf(-logit));
  }
}

// ---------------- launch ----------------
extern "C" void kernel_launch(void* const* d_in, const int* in_sizes, int n_in,
                              void* d_out, int out_size, void* d_ws, size_t ws_size,
                              hipStream_t stream) {
  const float* x   = (const float*)d_in[0];
  const int* ei    = (const int*)d_in[1];
  const float* W1  = (const float*)d_in[2];
  const float* b1  = (const float*)d_in[3];
  const float* W2  = (const float*)d_in[4];
  const float* b2  = (const float*)d_in[5];
  const float* Wm1 = (const float*)d_in[6];
  const float* bm1 = (const float*)d_in[7];
  const float* Wm2 = (const float*)d_in[8];
  const float* bm2 = (const float*)d_in[9];
  float* out = (float*)d_out;

  const int* src = ei;
  const int* dst = ei + NE;

  // workspace layout (high-water 92,708,864 B; round-1 proved ws_size >= 102.8 MB)
  char* ws = (char*)d_ws;
  int*   deg    = (int*)(ws + 0x000000);   // 400 KB
  int*   rs     = (int*)(ws + 0x080000);   // 400 KB (+4)
  int*   cursor = (int*)(ws + 0x100000);   // 400 KB
  float* dinv   = (float*)(ws + 0x180000); // 400 KB
  int*   bsum   = (int*)(ws + 0x200000);
  int*   boff   = (int*)(ws + 0x210000);
  unsigned short* Bp = (unsigned short*)(ws + 0x220000);  // 128 KB -> ends 0x240000
  uint2* sde    = (uint2*)(ws + 0x240000);  // 12.8 MB -> ends 15,159,296
  unsigned short* bufT = (unsigned short*)(ws + 0xE80000);   // 25.6 MB -> ends 40,804,352
  unsigned short* hbuf = (unsigned short*)(ws + 0x2700000);  // 25.6 MB -> ends 66,494,464
  unsigned short* vbuf = (unsigned short*)(ws + 0x4000000);  // 25.6 MB -> ends 92,708,864
  unsigned short* ubuf = bufT;

  const int gN = NB;
  const int gPart = (NE / 256) * 8;    // 50000: XCD-partitioned hist/fill
  const int gRow = (NN + 63) / 64;     // 1563
  const int gDual = (NN + 127) / 128;  // 782
  const int gAgg = (NN + 3) / 4;
  const int gEdge = 25000 / 4;

  // CSR build + weight prep
  k_zero<<<gN, 256, 0, stream>>>(deg);
  k_hist<<<gPart, 256, 0, stream>>>(dst, deg);
  k_scan1<<<gN, 256, 0, stream>>>(deg, cursor, bsum);
  k_scan2<<<1, 64, 0, stream>>>(bsum, boff);
  k_scan3<<<gN, 256, 0, stream>>>(deg, cursor, boff, rs, dinv);
  k_fill<<<gPart, 256, 0, stream>>>(src, dst, cursor, sde);
  k_prep<<<256, 256, 0, stream>>>(W1, W2, Wm1, Bp);

  // layer 1: T1' = dinv*(x@W1) (bf16, MFMA); h1 = agg (bf16)
  k_gemm_mfma_f32<<<gRow, 256, 0, stream>>>(x, Bp, bufT, dinv, NN);
  k_agg<<<gAgg, 256, 0, stream>>>(bufT, rs, sde, dinv, b1, hbuf);

  // layer 2: T2' = dinv*(h1@W2) (bf16, MFMA); h2 = agg (bf16)
  k_gemm_mfma<<<gRow, 256, 0, stream>>>(hbuf, Bp + 16384, bufT, dinv, NN);
  k_agg<<<gAgg, 256, 0, stream>>>(bufT, rs, sde, dinv, b2, hbuf);

  // u = h2 @ Wm1_top, v = h2 @ Wm1_bot (fused dual MFMA)
  k_gemm_dual<<<gDual, 512, 0, stream>>>(hbuf, Bp + 2 * 16384, ubuf, vbuf, NN);

  // edge epilogue
  k_edge<<<gEdge, 256, 0, stream>>>(ubuf, vbuf, sde, bm1, Wm2, bm2, out);
}